// Round 1
// baseline (99971.259 us; speedup 1.0000x reference)
//
#include <hip/hip_runtime.h>
#include <hip/hip_bf16.h>
#include <hip/hip_fp16.h>

typedef _Float16 f16;
typedef _Float16 f16x2 __attribute__((ext_vector_type(2)));
typedef _Float16 f16x4 __attribute__((ext_vector_type(4)));
typedef _Float16 f16x8 __attribute__((ext_vector_type(8)));
typedef float f32x4 __attribute__((ext_vector_type(4)));

#define S_LEN 16384
#define HID 512
#define NRULES 2048
#define NWG 8   // workgroups per scan

#if __has_builtin(__builtin_amdgcn_rcpf)
#define RCPF(x) __builtin_amdgcn_rcpf(x)
#else
#define RCPF(x) (1.0f/(x))
#endif

__device__ __forceinline__ float sigf(float x){
  return RCPF(1.0f + __expf(-x));
}
__device__ __forceinline__ float tanh_fast(float x){
  float ax = fabsf(x);
  float e = __expf(-2.0f*ax);
  float t = (1.0f - e) * RCPF(1.0f + e);
  return x >= 0.0f ? t : -t;
}
__device__ __forceinline__ float dot2(f16x2 a, f16x2 b, float c){
#if __has_builtin(__builtin_amdgcn_fdot2)
  return __builtin_amdgcn_fdot2(a, b, c, false);
#else
  return c + (float)a.x*(float)b.x + (float)a.y*(float)b.y;
#endif
}

// ---------------- gather x = [emb[shifted], emb[parent]] as f16 ----------------
__global__ __launch_bounds__(256) void gather_x(
    const float* __restrict__ emb, const int* __restrict__ act,
    const int* __restrict__ par, f16* __restrict__ X)
{
  const int t = blockIdx.x, lid = threadIdx.x;
  const int ia = (t == 0) ? 0 : (act[t-1] + 1);
  const int ip = par[t] + 1;
  const int half = lid >> 7;            // 0: action embedding, 1: parent embedding
  const int k = (lid & 127) << 2;
  const float* src = emb + (size_t)(half ? ip : ia) * 512 + k;
  float4 v = *(const float4*)src;
  f16x4 o; o.x=(f16)v.x; o.y=(f16)v.y; o.z=(f16)v.z; o.w=(f16)v.w;
  *(f16x4*)&X[(size_t)t*1024 + (half<<9) + k] = o;
}

// ---------------- fp32 -> f16 convert ----------------
__global__ __launch_bounds__(256) void cvt_k(const float* __restrict__ in,
                                             f16* __restrict__ out, int n)
{
  const int i = (blockIdx.x*256 + threadIdx.x) << 2;
  if (i >= n) return;
  float4 v = *(const float4*)&in[i];
  f16x4 o; o.x=(f16)v.x; o.y=(f16)v.y; o.z=(f16)v.z; o.w=(f16)v.w;
  *(f16x4*)&out[i] = o;
}

// ---------------- f16 MFMA GEMM: C[M,N] = A[M,K] @ B[N,K]^T + bias ----------------
// M,N multiples of 128; K multiple of 32.
template<typename OutT>
__global__ __launch_bounds__(256) void gemm_f16(
    const f16* __restrict__ A, const f16* __restrict__ B,
    const float* __restrict__ bias, OutT* __restrict__ C,
    int M, int N, int K)
{
  __shared__ __align__(16) f16 At[4][128][8];
  __shared__ __align__(16) f16 Bt[4][128][8];
  const int lid = threadIdx.x;
  const int mtiles = M >> 7;
  const int bm = blockIdx.x % mtiles;
  const int bn = blockIdx.x / mtiles;
  const int m0 = bm << 7, n0 = bn << 7;
  const int lane = lid & 63, w = lid >> 6;
  const int wm = (w >> 1) << 6, wn = (w & 1) << 6;
  f32x4 acc[4][4] = {};
  const int nk = K >> 5;
  const int row1 = lid >> 2, j1 = lid & 3;
  for (int kt = 0; kt < nk; ++kt){
    const int kb = kt << 5;
    *(f16x8*)&At[j1][row1][0]    = *(const f16x8*)&A[(size_t)(m0+row1)*K    + kb + j1*8];
    *(f16x8*)&At[j1][row1+64][0] = *(const f16x8*)&A[(size_t)(m0+row1+64)*K + kb + j1*8];
    *(f16x8*)&Bt[j1][row1][0]    = *(const f16x8*)&B[(size_t)(n0+row1)*K    + kb + j1*8];
    *(f16x8*)&Bt[j1][row1+64][0] = *(const f16x8*)&B[(size_t)(n0+row1+64)*K + kb + j1*8];
    __syncthreads();
    const int kc = lane >> 4, rr = lane & 15;
    f16x8 aF[4], bF[4];
    #pragma unroll
    for (int m=0;m<4;m++) aF[m] = *(const f16x8*)&At[kc][wm + m*16 + rr][0];
    #pragma unroll
    for (int n=0;n<4;n++) bF[n] = *(const f16x8*)&Bt[kc][wn + n*16 + rr][0];
    #pragma unroll
    for (int m=0;m<4;m++)
      #pragma unroll
      for (int n=0;n<4;n++)
        acc[m][n] = __builtin_amdgcn_mfma_f32_16x16x32_f16(aF[m], bF[n], acc[m][n], 0,0,0);
    __syncthreads();
  }
  const int rr = lane & 15, rg = lane >> 4;
  #pragma unroll
  for (int n=0;n<4;n++){
    const int gcol = n0 + wn + n*16 + rr;
    const float bv = bias[gcol];
    #pragma unroll
    for (int m=0;m<4;m++){
      #pragma unroll
      for (int r=0;r<4;r++){
        const int grow = m0 + wm + m*16 + rg*4 + r;
        C[(size_t)grow*N + gcol] = (OutT)(acc[m][n][r] + bv);
      }
    }
  }
}

// ---------------- persistent GRU scan (one layer) ----------------
// NWG=8 workgroups x 256 threads. 4 threads per h-row (K-slice of 128 each),
// W_hh rows (r,z,n) for that row held as packed f16 in VGPRs.
// h exchanged via global hbuf (double-buffered), device-scope spin barrier.
__global__ __launch_bounds__(256, 1) void gru_scan(
    const float* __restrict__ W_hh, const float* __restrict__ b_hh,
    const f16* __restrict__ xi, const float* __restrict__ h0,
    f16* __restrict__ hseq, float* hbuf, int* bar, int nsteps)
{
  const int lid = threadIdx.x;
  const int wg = blockIdx.x;
  const int ksub = lid & 3;
  const int hrow = (wg << 6) + (lid >> 2);   // 0..511
  const bool owner = (ksub == 0);

  // load & pack weights: pairs p = ksub + 4i, k = 2p, 2p+1
  f16x2 wr[64], wz[64], wv[64];
  #pragma unroll
  for (int i=0;i<64;i++){
    const int k0 = (ksub + (i<<2)) << 1;
    float2 a = *(const float2*)&W_hh[(size_t)hrow*512        + k0];
    float2 b = *(const float2*)&W_hh[(size_t)(512+hrow)*512  + k0];
    float2 c = *(const float2*)&W_hh[(size_t)(1024+hrow)*512 + k0];
    wr[i].x=(f16)a.x; wr[i].y=(f16)a.y;
    wz[i].x=(f16)b.x; wz[i].y=(f16)b.y;
    wv[i].x=(f16)c.x; wv[i].y=(f16)c.y;
  }

  __shared__ f16x2 hlds[256];
  {
    float2 h2 = *(const float2*)&h0[lid*2];
    f16x2 hp; hp.x=(f16)h2.x; hp.y=(f16)h2.y;
    hlds[lid] = hp;
  }
  float h_old=0.f, bhr=0.f, bhz=0.f, bhn=0.f, xr=0.f, xz=0.f, xn=0.f;
  if (owner){
    h_old = h0[hrow];
    bhr = b_hh[hrow]; bhz = b_hh[512+hrow]; bhn = b_hh[1024+hrow];
    xr = (float)xi[hrow]; xz = (float)xi[512+hrow]; xn = (float)xi[1024+hrow];
  }
  __syncthreads();

  for (int t=0; t<nsteps; ++t){
    float ar=0.f, az=0.f, an=0.f;
    #pragma unroll
    for (int i=0;i<64;i++){
      f16x2 hv = hlds[ksub + (i<<2)];
      ar = dot2(wr[i], hv, ar);
      az = dot2(wz[i], hv, az);
      an = dot2(wv[i], hv, an);
    }
    ar += __shfl_xor(ar, 1); ar += __shfl_xor(ar, 2);
    az += __shfl_xor(az, 1); az += __shfl_xor(az, 2);
    an += __shfl_xor(an, 1); an += __shfl_xor(an, 2);
    if (owner){
      float r  = sigf(xr + ar + bhr);
      float z  = sigf(xz + az + bhz);
      float nl = tanh_fast(xn + r*(an + bhn));
      float hnew = (1.0f - z)*nl + z*h_old;
      h_old = hnew;
      hbuf[((t+1)&1)*512 + hrow] = hnew;
      hseq[(size_t)t*512 + hrow] = (f16)hnew;
      if (t+1 < nsteps){
        const f16* xp = xi + (size_t)(t+1)*1536;
        xr = (float)xp[hrow]; xz = (float)xp[512+hrow]; xn = (float)xp[1024+hrow];
      }
    }
    __syncthreads();
    if (lid == 0){
      __hip_atomic_fetch_add(bar, 1, __ATOMIC_RELEASE, __HIP_MEMORY_SCOPE_AGENT);
      const int target = (t+1) * NWG;
      while (__hip_atomic_load(bar, __ATOMIC_RELAXED, __HIP_MEMORY_SCOPE_AGENT) < target)
        __builtin_amdgcn_s_sleep(1);
    }
    __syncthreads();
    __builtin_amdgcn_fence(__ATOMIC_ACQUIRE, "agent");
    {
      float2 h2 = *(const float2*)&hbuf[((t+1)&1)*512 + lid*2];
      f16x2 hp; hp.x=(f16)h2.x; hp.y=(f16)h2.y;
      hlds[lid] = hp;
    }
    __syncthreads();
  }
}

// ---------------- row-wise log_softmax over 2048, in place ----------------
__global__ __launch_bounds__(256) void logsoftmax_k(float* __restrict__ lp)
{
  const int t = blockIdx.x, lid = threadIdx.x;
  float* row = lp + (size_t)t*2048;
  float4 a = ((const float4*)row)[lid*2];
  float4 b = ((const float4*)row)[lid*2+1];
  float m = fmaxf(fmaxf(fmaxf(a.x,a.y),fmaxf(a.z,a.w)),
                  fmaxf(fmaxf(b.x,b.y),fmaxf(b.z,b.w)));
  #pragma unroll
  for (int off=1; off<64; off<<=1) m = fmaxf(m, __shfl_xor(m, off));
  __shared__ float redm[4], reds[4];
  const int lane = lid & 63, wvi = lid >> 6;
  if (lane==0) redm[wvi] = m;
  __syncthreads();
  m = fmaxf(fmaxf(redm[0],redm[1]), fmaxf(redm[2],redm[3]));
  float s = __expf(a.x-m)+__expf(a.y-m)+__expf(a.z-m)+__expf(a.w-m)
          + __expf(b.x-m)+__expf(b.y-m)+__expf(b.z-m)+__expf(b.w-m);
  #pragma unroll
  for (int off=1; off<64; off<<=1) s += __shfl_xor(s, off);
  if (lane==0) reds[wvi] = s;
  __syncthreads();
  s = reds[0]+reds[1]+reds[2]+reds[3];
  const float lg = m + __logf(s);
  a.x-=lg; a.y-=lg; a.z-=lg; a.w-=lg;
  b.x-=lg; b.y-=lg; b.z-=lg; b.w-=lg;
  ((float4*)row)[lid*2]   = a;
  ((float4*)row)[lid*2+1] = b;
}

// ---------------- values head: one wave per timestep ----------------
__global__ __launch_bounds__(256) void values_k(
    const f16* __restrict__ h1, const float* __restrict__ vW,
    const float* __restrict__ vb, float* __restrict__ outv, int S)
{
  const int gt = (int)((blockIdx.x*256 + threadIdx.x) >> 6);
  if (gt >= S) return;
  const int lane = threadIdx.x & 63;
  const f16* rowp = h1 + (size_t)gt*512;
  float s = 0.f;
  #pragma unroll
  for (int j=0;j<8;j++){
    const int k = lane + (j<<6);
    s += (float)rowp[k] * vW[k];
  }
  #pragma unroll
  for (int off=32; off; off>>=1) s += __shfl_down(s, off);
  if (lane==0) outv[gt] = s + vb[0];
}

extern "C" void kernel_launch(void* const* d_in, const int* in_sizes, int n_in,
                              void* d_out, int out_size, void* d_ws, size_t ws_size,
                              hipStream_t stream) {
  const float* init = (const float*)d_in[0];
  const float* emb  = (const float*)d_in[1];
  const float* Wih0 = (const float*)d_in[2];
  const float* Whh0 = (const float*)d_in[3];
  const float* bih0 = (const float*)d_in[4];
  const float* bhh0 = (const float*)d_in[5];
  const float* Wih1 = (const float*)d_in[6];
  const float* Whh1 = (const float*)d_in[7];
  const float* bih1 = (const float*)d_in[8];
  const float* bhh1 = (const float*)d_in[9];
  const float* actW = (const float*)d_in[10];
  const float* actb = (const float*)d_in[11];
  const float* valW = (const float*)d_in[12];
  const float* valb = (const float*)d_in[13];
  const int*   acts = (const int*)d_in[14];
  const int*   pars = (const int*)d_in[15];
  float* out = (float*)d_out;
  char*  w   = (char*)d_ws;

  // ws layout (~38.5 MB):
  //   [0, 33554432)            X f16 [S,1024]; later overlaid by h0seq/h1seq
  //   [33554432, +3145728)     W_ih0 f16
  //   [36700160, +1572864)     W_ih1 f16
  //   [38273024, +2097152)     action_W f16
  //   [40370176, +4096)        hbuf (2 x 512 fp32)
  //   [40374272, +4)           barrier counter
  f16* X      = (f16*)(w + 0);
  f16* h0seq  = (f16*)(w + 0);
  f16* h1seq  = (f16*)(w + 16777216);
  f16* Wih0h  = (f16*)(w + 33554432);
  f16* Wih1h  = (f16*)(w + 36700160);
  f16* actWh  = (f16*)(w + 38273024);
  float* hbuf = (float*)(w + 40370176);
  int* bar    = (int*)(w + 40374272);
  // xi buffer lives in d_out's first 50 MB (dead before logits GEMM writes C)
  f16* xi = (f16*)d_out;

  gather_x<<<S_LEN, 256, 0, stream>>>(emb, acts, pars, X);
  cvt_k<<<1536, 256, 0, stream>>>(Wih0, Wih0h, 1536*1024);
  cvt_k<<<768,  256, 0, stream>>>(Wih1, Wih1h, 1536*512);
  cvt_k<<<1024, 256, 0, stream>>>(actW, actWh, 2048*512);

  // xi0 = X @ W_ih0^T + b_ih0   [S,1536]
  gemm_f16<f16><<<128*12, 256, 0, stream>>>(X, Wih0h, bih0, xi, S_LEN, 1536, 1024);
  hipMemsetAsync(bar, 0, 4, stream);
  gru_scan<<<NWG, 256, 0, stream>>>(Whh0, bhh0, xi, init, h0seq, hbuf, bar, S_LEN);

  // xi1 = h0seq @ W_ih1^T + b_ih1   [S,1536]
  gemm_f16<f16><<<128*12, 256, 0, stream>>>(h0seq, Wih1h, bih1, xi, S_LEN, 1536, 512);
  hipMemsetAsync(bar, 0, 4, stream);
  gru_scan<<<NWG, 256, 0, stream>>>(Whh1, bhh1, xi, init + 512, h1seq, hbuf, bar, S_LEN);

  // logits = h1seq @ action_W^T + action_b -> d_out, then log_softmax in place
  gemm_f16<float><<<128*16, 256, 0, stream>>>(h1seq, actWh, actb, out, S_LEN, NRULES, 512);
  logsoftmax_k<<<S_LEN, 256, 0, stream>>>(out);
  values_k<<<S_LEN/4, 256, 0, stream>>>(h1seq, valW, valb, out + (size_t)S_LEN*NRULES, S_LEN);
}

// Round 4
// 66967.902 us; speedup vs baseline: 1.4928x; 1.4928x over previous
//
#include <hip/hip_runtime.h>
#include <hip/hip_bf16.h>
#include <hip/hip_fp16.h>

typedef _Float16 f16;
typedef _Float16 f16x2 __attribute__((ext_vector_type(2)));
typedef _Float16 f16x4 __attribute__((ext_vector_type(4)));
typedef _Float16 f16x8 __attribute__((ext_vector_type(8)));
typedef float f32x4 __attribute__((ext_vector_type(4)));

#define S_LEN 16384
#define NRULES 2048
#define NT 24          // 8 layer0 blocks + 16 layer1 blocks, grid == NT (co-resident)

// ws control offsets
#define CTRL_OFF 38797312
#define H0_OFF (CTRL_OFF + 7168)
#define H1_OFF (H0_OFF + 2048)

#if __has_builtin(__builtin_amdgcn_rcpf)
#define RCPF(x) __builtin_amdgcn_rcpf(x)
#else
#define RCPF(x) (1.0f/(x))
#endif

__device__ __forceinline__ float sigf(float x){ return RCPF(1.0f + __expf(-x)); }
__device__ __forceinline__ float tanh_fast(float x){
  float ax = fabsf(x);
  float e = __expf(-2.0f*ax);
  float t = (1.0f - e) * RCPF(1.0f + e);
  return x >= 0.0f ? t : -t;
}
__device__ __forceinline__ float dot2(f16x2 a, f16x2 b, float c){
#if __has_builtin(__builtin_amdgcn_fdot2)
  return __builtin_amdgcn_fdot2(a, b, c, false);
#else
  return c + (float)a.x*(float)b.x + (float)a.y*(float)b.y;
#endif
}

// ---------------- gather x = [emb[shifted], emb[parent]] as f16 ----------------
__global__ __launch_bounds__(256) void gather_x(
    const float* __restrict__ emb, const int* __restrict__ act,
    const int* __restrict__ par, f16* __restrict__ X)
{
  const int t = blockIdx.x, lid = threadIdx.x;
  const int ia = (t == 0) ? 0 : (act[t-1] + 1);
  const int ip = par[t] + 1;
  const int half = lid >> 7;
  const int k = (lid & 127) << 2;
  const float* src = emb + (size_t)(half ? ip : ia) * 512 + k;
  float4 v = *(const float4*)src;
  f16x4 o; o.x=(f16)v.x; o.y=(f16)v.y; o.z=(f16)v.z; o.w=(f16)v.w;
  *(f16x4*)&X[(size_t)t*1024 + (half<<9) + k] = o;
}

// ---------------- fp32 -> f16 convert ----------------
__global__ __launch_bounds__(256) void cvt_k(const float* __restrict__ in,
                                             f16* __restrict__ out, int n)
{
  const int i = (blockIdx.x*256 + threadIdx.x) << 2;
  if (i >= n) return;
  float4 v = *(const float4*)&in[i];
  f16x4 o; o.x=(f16)v.x; o.y=(f16)v.y; o.z=(f16)v.z; o.w=(f16)v.w;
  *(f16x4*)&out[i] = o;
}

// ---------------- control init + h-state seed (re-run every call) ----------------
__global__ __launch_bounds__(1024) void init_ctrl(const float* __restrict__ init, char* ws)
{
  const int lid = threadIdx.x;
  int* C = (int*)(ws + CTRL_OFF);
  for (int i = lid; i < 1792; i += 1024) C[i] = 0;   // barrier counter + spare
  f16* h0b = (f16*)(ws + H0_OFF);
  f16* h1b = (f16*)(ws + H1_OFF);
  if (lid < 512) h0b[512 + lid] = (f16)init[lid];          // h0buf slot1 = h0 init
  else           h1b[512 + (lid-512)] = (f16)init[lid];    // h1buf slot1 = h1 init
}

// ---------------- f16 MFMA GEMM: C[M,N] = A[M,K] @ B[N,K]^T + bias ----------------
template<typename OutT>
__global__ __launch_bounds__(256) void gemm_f16(
    const f16* __restrict__ A, const f16* __restrict__ B,
    const float* __restrict__ bias, OutT* __restrict__ C,
    int M, int N, int K)
{
  __shared__ __align__(16) f16 At[4][128][8];
  __shared__ __align__(16) f16 Bt[4][128][8];
  const int lid = threadIdx.x;
  const int mtiles = M >> 7;
  const int bm = blockIdx.x % mtiles;
  const int bn = blockIdx.x / mtiles;
  const int m0 = bm << 7, n0 = bn << 7;
  const int lane = lid & 63, w = lid >> 6;
  const int wm = (w >> 1) << 6, wn = (w & 1) << 6;
  f32x4 acc[4][4] = {};
  const int nk = K >> 5;
  const int row1 = lid >> 2, j1 = lid & 3;
  for (int kt = 0; kt < nk; ++kt){
    const int kb = kt << 5;
    *(f16x8*)&At[j1][row1][0]    = *(const f16x8*)&A[(size_t)(m0+row1)*K    + kb + j1*8];
    *(f16x8*)&At[j1][row1+64][0] = *(const f16x8*)&A[(size_t)(m0+row1+64)*K + kb + j1*8];
    *(f16x8*)&Bt[j1][row1][0]    = *(const f16x8*)&B[(size_t)(n0+row1)*K    + kb + j1*8];
    *(f16x8*)&Bt[j1][row1+64][0] = *(const f16x8*)&B[(size_t)(n0+row1+64)*K + kb + j1*8];
    __syncthreads();
    const int kc = lane >> 4, rr = lane & 15;
    f16x8 aF[4], bF[4];
    #pragma unroll
    for (int m=0;m<4;m++) aF[m] = *(const f16x8*)&At[kc][wm + m*16 + rr][0];
    #pragma unroll
    for (int n=0;n<4;n++) bF[n] = *(const f16x8*)&Bt[kc][wn + n*16 + rr][0];
    #pragma unroll
    for (int m=0;m<4;m++)
      #pragma unroll
      for (int n=0;n<4;n++)
        acc[m][n] = __builtin_amdgcn_mfma_f32_16x16x32_f16(aF[m], bF[n], acc[m][n], 0,0,0);
    __syncthreads();
  }
  const int rr = lane & 15, rg = lane >> 4;
  #pragma unroll
  for (int n=0;n<4;n++){
    const int gcol = n0 + wn + n*16 + rr;
    const float bv = bias[gcol];
    #pragma unroll
    for (int m=0;m<4;m++){
      #pragma unroll
      for (int r=0;r<4;r++){
        const int grow = m0 + wm + m*16 + rg*4 + r;
        C[(size_t)grow*N + gcol] = (OutT)(acc[m][n][r] + bv);
      }
    }
  }
}

// ---------------- fused two-layer pipelined GRU scan ----------------
// grid = NT = 24 blocks exactly (no election). Blocks 0..7 = layer0
// (64 rows each, 4 thr/row, K=128/thr, Whh0 in VGPRs). Blocks 8..23 = layer1
// (32 rows each, 8 thr/row, Wih1+Whh1 in VGPRs -> middle GEMM fused away).
// Round q: layer0 computes h0[q] (q<S), layer1 computes h1[q-1] (q>=1).
// Sync = round-1-PROVEN pattern: plain stores, __syncthreads drain, release
// fetch_add on one agent counter, relaxed spin + s_sleep (capped), acquire
// agent fence, plain reloads. Caps convert any deadlock into bounded abort.
__global__ __launch_bounds__(256, 1) void scan_fused(
    const float* __restrict__ Whh0, const float* __restrict__ bhh0,
    const float* __restrict__ Wih1, const float* __restrict__ bih1,
    const float* __restrict__ Whh1, const float* __restrict__ bhh1,
    const float* __restrict__ init, const f16* __restrict__ xi0,
    f16* __restrict__ h1seq, char* ws)
{
  int* bar = (int*)(ws + CTRL_OFF) + 8;
  f16* h0buf = (f16*)(ws + H0_OFF);
  f16* h1buf = (f16*)(ws + H1_OFF);
  const int lid = threadIdx.x;
  const int ticket = blockIdx.x;
  __shared__ f16x2 hx[256];
  __shared__ f16x2 hh[256];
  __shared__ int s_abort;
  if (lid == 0) s_abort = 0;
  __syncthreads();

#define GBAR(Q) do { \
    __syncthreads(); \
    if (lid == 0){ \
      __hip_atomic_fetch_add(bar, 1, __ATOMIC_RELEASE, __HIP_MEMORY_SCOPE_AGENT); \
      const int tgt = ((Q)+1) * NT; int it = 0; \
      while (__hip_atomic_load(bar, __ATOMIC_RELAXED, __HIP_MEMORY_SCOPE_AGENT) < tgt){ \
        __builtin_amdgcn_s_sleep(1); \
        if (++it > 4000000){ s_abort = 1; break; } \
      } \
    } \
    __syncthreads(); \
    if (s_abort) return; \
    __builtin_amdgcn_fence(__ATOMIC_ACQUIRE, "agent"); \
  } while(0)

  if (ticket < 8){
    // ================= layer 0 =================
    const int ksub = lid & 3, row = (ticket << 6) + (lid >> 2);
    const bool owner = (ksub == 0);
    f16x2 wr[64], wz[64], wn[64];
    #pragma unroll
    for (int i=0;i<64;i++){
      const int k0 = (ksub + (i<<2)) << 1;
      float2 a = *(const float2*)&Whh0[(size_t)row*512         + k0];
      float2 b = *(const float2*)&Whh0[(size_t)(512+row)*512   + k0];
      float2 c = *(const float2*)&Whh0[(size_t)(1024+row)*512  + k0];
      wr[i].x=(f16)a.x; wr[i].y=(f16)a.y;
      wz[i].x=(f16)b.x; wz[i].y=(f16)b.y;
      wn[i].x=(f16)c.x; wn[i].y=(f16)c.y;
    }
    float h_old=0.f, bhr=0.f, bhz=0.f, bhn=0.f;
    if (owner){ h_old=init[row]; bhr=bhh0[row]; bhz=bhh0[512+row]; bhn=bhh0[1024+row]; }

    for (int q=0; q<=S_LEN; ++q){
      if (q < S_LEN){
        if (lid < 128)                 // stage h0[q-1]
          ((int2*)hx)[lid] = *(const int2*)&h0buf[((q+1)&1)*512 + lid*4];
        float xr=0.f, xz=0.f, xn=0.f;
        if (owner){                    // immutable input gates
          const f16* xp = xi0 + (size_t)q*1536;
          xr=(float)xp[row]; xz=(float)xp[512+row]; xn=(float)xp[1024+row];
        }
        __syncthreads();
        float ar=0.f, az=0.f, an=0.f;
        #pragma unroll
        for (int i=0;i<64;i++){
          f16x2 hv = hx[ksub + (i<<2)];
          ar = dot2(wr[i], hv, ar); az = dot2(wz[i], hv, az); an = dot2(wn[i], hv, an);
        }
        ar += __shfl_xor(ar,1); ar += __shfl_xor(ar,2);
        az += __shfl_xor(az,1); az += __shfl_xor(az,2);
        an += __shfl_xor(an,1); an += __shfl_xor(an,2);
        if (owner){
          float r  = sigf(xr + ar + bhr);
          float z  = sigf(xz + az + bhz);
          float nl = tanh_fast(xn + r*(an + bhn));
          float hnew = (1.0f - z)*nl + z*h_old;
          h_old = hnew;
          h0buf[(q&1)*512 + row] = (f16)hnew;
        }
      }
      if (q < S_LEN) GBAR(q);
    }
  } else {
    // ================= layer 1 (fused W_ih1 + W_hh1) =================
    const int tk2 = ticket - 8;
    const int ksub = lid & 7, row = (tk2 << 5) + (lid >> 3);
    const bool owner = (ksub == 0);
    f16x2 ur[32], uz[32], un[32], vr[32], vz[32], vn[32];
    #pragma unroll
    for (int i=0;i<32;i++){
      const int k0 = (ksub + (i<<3)) << 1;
      float2 a = *(const float2*)&Wih1[(size_t)row*512        + k0];
      float2 b = *(const float2*)&Wih1[(size_t)(512+row)*512  + k0];
      float2 c = *(const float2*)&Wih1[(size_t)(1024+row)*512 + k0];
      float2 d = *(const float2*)&Whh1[(size_t)row*512        + k0];
      float2 e = *(const float2*)&Whh1[(size_t)(512+row)*512  + k0];
      float2 f = *(const float2*)&Whh1[(size_t)(1024+row)*512 + k0];
      ur[i].x=(f16)a.x; ur[i].y=(f16)a.y;
      uz[i].x=(f16)b.x; uz[i].y=(f16)b.y;
      un[i].x=(f16)c.x; un[i].y=(f16)c.y;
      vr[i].x=(f16)d.x; vr[i].y=(f16)d.y;
      vz[i].x=(f16)e.x; vz[i].y=(f16)e.y;
      vn[i].x=(f16)f.x; vn[i].y=(f16)f.y;
    }
    float h_old=0.f, bir=0.f,biz=0.f,bin=0.f, bhr=0.f,bhz=0.f,bhn=0.f;
    if (owner){
      h_old=init[512+row];
      bir=bih1[row]; biz=bih1[512+row]; bin=bih1[1024+row];
      bhr=bhh1[row]; bhz=bhh1[512+row]; bhn=bhh1[1024+row];
    }

    for (int q=0; q<=S_LEN; ++q){
      if (q >= 1){
        if (lid < 128){                // stage x = h0[q-1]
          ((int2*)hx)[lid] = *(const int2*)&h0buf[((q+1)&1)*512 + lid*4];
        } else {                       // stage h1[q-2]
          const int l = lid - 128;
          ((int2*)hh)[l] = *(const int2*)&h1buf[(q&1)*512 + l*4];
        }
        __syncthreads();
        float ir=0.f, iz=0.f, in_=0.f, hr=0.f, hz=0.f, hn=0.f;
        #pragma unroll
        for (int i=0;i<32;i++){
          f16x2 xv = hx[ksub + (i<<3)];
          f16x2 hv = hh[ksub + (i<<3)];
          ir = dot2(ur[i], xv, ir); iz = dot2(uz[i], xv, iz); in_ = dot2(un[i], xv, in_);
          hr = dot2(vr[i], hv, hr); hz = dot2(vz[i], hv, hz); hn  = dot2(vn[i], hv, hn);
        }
        #pragma unroll
        for (int d=1; d<8; d<<=1){
          ir += __shfl_xor(ir,d); iz += __shfl_xor(iz,d); in_ += __shfl_xor(in_,d);
          hr += __shfl_xor(hr,d); hz += __shfl_xor(hz,d); hn  += __shfl_xor(hn,d);
        }
        if (owner){
          float r  = sigf(ir + bir + hr + bhr);
          float z  = sigf(iz + biz + hz + bhz);
          float nl = tanh_fast(in_ + bin + r*(hn + bhn));
          float hnew = (1.0f - z)*nl + z*h_old;
          h_old = hnew;
          h1buf[((q+1)&1)*512 + row] = (f16)hnew;
          h1seq[(size_t)(q-1)*512 + row] = (f16)hnew;
        }
      } else {
        __syncthreads();
      }
      if (q < S_LEN) GBAR(q);
    }
  }
#undef GBAR
}

// ---------------- row-wise log_softmax over 2048, in place ----------------
__global__ __launch_bounds__(256) void logsoftmax_k(float* __restrict__ lp)
{
  const int t = blockIdx.x, lid = threadIdx.x;
  float* row = lp + (size_t)t*2048;
  float4 a = ((const float4*)row)[lid*2];
  float4 b = ((const float4*)row)[lid*2+1];
  float m = fmaxf(fmaxf(fmaxf(a.x,a.y),fmaxf(a.z,a.w)),
                  fmaxf(fmaxf(b.x,b.y),fmaxf(b.z,b.w)));
  #pragma unroll
  for (int off=1; off<64; off<<=1) m = fmaxf(m, __shfl_xor(m, off));
  __shared__ float redm[4], reds[4];
  const int lane = lid & 63, wvi = lid >> 6;
  if (lane==0) redm[wvi] = m;
  __syncthreads();
  m = fmaxf(fmaxf(redm[0],redm[1]), fmaxf(redm[2],redm[3]));
  float s = __expf(a.x-m)+__expf(a.y-m)+__expf(a.z-m)+__expf(a.w-m)
          + __expf(b.x-m)+__expf(b.y-m)+__expf(b.z-m)+__expf(b.w-m);
  #pragma unroll
  for (int off=1; off<64; off<<=1) s += __shfl_xor(s, off);
  if (lane==0) reds[wvi] = s;
  __syncthreads();
  s = reds[0]+reds[1]+reds[2]+reds[3];
  const float lg = m + __logf(s);
  a.x-=lg; a.y-=lg; a.z-=lg; a.w-=lg;
  b.x-=lg; b.y-=lg; b.z-=lg; b.w-=lg;
  ((float4*)row)[lid*2]   = a;
  ((float4*)row)[lid*2+1] = b;
}

// ---------------- values head: one wave per timestep ----------------
__global__ __launch_bounds__(256) void values_k(
    const f16* __restrict__ h1, const float* __restrict__ vW,
    const float* __restrict__ vb, float* __restrict__ outv, int S)
{
  const int gt = (int)((blockIdx.x*256 + threadIdx.x) >> 6);
  if (gt >= S) return;
  const int lane = threadIdx.x & 63;
  const f16* rowp = h1 + (size_t)gt*512;
  float s = 0.f;
  #pragma unroll
  for (int j=0;j<8;j++){
    const int k = lane + (j<<6);
    s += (float)rowp[k] * vW[k];
  }
  #pragma unroll
  for (int off=32; off; off>>=1) s += __shfl_down(s, off);
  if (lane==0) outv[gt] = s + vb[0];
}

extern "C" void kernel_launch(void* const* d_in, const int* in_sizes, int n_in,
                              void* d_out, int out_size, void* d_ws, size_t ws_size,
                              hipStream_t stream) {
  const float* init = (const float*)d_in[0];
  const float* emb  = (const float*)d_in[1];
  const float* Wih0 = (const float*)d_in[2];
  const float* Whh0 = (const float*)d_in[3];
  const float* bih0 = (const float*)d_in[4];
  const float* bhh0 = (const float*)d_in[5];
  const float* Wih1 = (const float*)d_in[6];
  const float* Whh1 = (const float*)d_in[7];
  const float* bih1 = (const float*)d_in[8];
  const float* bhh1 = (const float*)d_in[9];
  const float* actW = (const float*)d_in[10];
  const float* actb = (const float*)d_in[11];
  const float* valW = (const float*)d_in[12];
  const float* valb = (const float*)d_in[13];
  const int*   acts = (const int*)d_in[14];
  const int*   pars = (const int*)d_in[15];
  float* out = (float*)d_out;
  char*  w   = (char*)d_ws;

  // ws: [0,32MB) X f16 [S,1024] (dead after GEMM0; h1seq overlays [0,16MB))
  //     [33554432,+3MB) Wih0h   [36700160,+2MB) actWh   [CTRL_OFF..) control
  f16* X      = (f16*)(w + 0);
  f16* h1seq  = (f16*)(w + 0);
  f16* Wih0h  = (f16*)(w + 33554432);
  f16* actWh  = (f16*)(w + 36700160);
  // xi0 f16 [S,1536] = 48MB lives in d_out (dead before logits GEMM writes it)
  f16* xi0 = (f16*)d_out;

  gather_x<<<S_LEN, 256, 0, stream>>>(emb, acts, pars, X);
  cvt_k<<<1536, 256, 0, stream>>>(Wih0, Wih0h, 1536*1024);
  cvt_k<<<1024, 256, 0, stream>>>(actW, actWh, 2048*512);
  init_ctrl<<<1, 1024, 0, stream>>>(init, w);

  // xi0 = X @ W_ih0^T + b_ih0   [S,1536]
  gemm_f16<f16><<<128*12, 256, 0, stream>>>(X, Wih0h, bih0, xi0, S_LEN, 1536, 1024);

  // fused two-layer pipelined scan (layer1's input GEMM folded in)
  scan_fused<<<NT, 256, 0, stream>>>(Whh0, bhh0, Wih1, bih1, Whh1, bhh1,
                                     init, xi0, h1seq, w);

  // logits = h1seq @ action_W^T + action_b -> d_out, then log_softmax in place
  gemm_f16<float><<<128*16, 256, 0, stream>>>(h1seq, actWh, actb, out, S_LEN, NRULES, 512);
  logsoftmax_k<<<S_LEN, 256, 0, stream>>>(out);
  values_k<<<S_LEN/4, 256, 0, stream>>>(h1seq, valW, valb, out + (size_t)S_LEN*NRULES, S_LEN);
}

// Round 5
// 35228.394 us; speedup vs baseline: 2.8378x; 1.9010x over previous
//
#include <hip/hip_runtime.h>
#include <hip/hip_bf16.h>
#include <hip/hip_fp16.h>

typedef _Float16 f16;
typedef _Float16 f16x2 __attribute__((ext_vector_type(2)));
typedef _Float16 f16x4 __attribute__((ext_vector_type(4)));
typedef _Float16 f16x8 __attribute__((ext_vector_type(8)));
typedef float f32x4 __attribute__((ext_vector_type(4)));
typedef unsigned long long u64;

#define S_LEN 16384
#define NRULES 2048
#define CAP 2000000   // spin cap: converts any protocol failure into bounded abort

// ---- ws layout (bytes) ----
#define H0SEQ_OFF 0u                    // 16 MB packed f16x2 cells [S][256]
#define H0FLG_OFF (16u*1024*1024)       // 8 flags, 128B apart (4 KB)
#define H1SEQ_OFF (17u*1024*1024)       // 16 MB packed f16 [S][512]
#define ACTW_OFF  (33u*1024*1024)       // 2 MB f16 action_W
#define WIH0_OFF  (35u*1024*1024)       // 3 MB f16 W_ih0
#define HBUF0_OFF (38u*1024*1024)       // 2*256 u64 tagged cells (4 KB)
#define HBUF1_OFF (38u*1024*1024+8192)  // 2*256 u64 tagged cells (4 KB)
// X (f16 [S,1024], 32 MB) lives in d_out[48MB,80MB); xi0 (f16 [S,1536], 48 MB) in d_out[0,48MB)

#if __has_builtin(__builtin_amdgcn_rcpf)
#define RCPF(x) __builtin_amdgcn_rcpf(x)
#else
#define RCPF(x) (1.0f/(x))
#endif

union F2U { f16x2 f; unsigned u; };

__device__ __forceinline__ float sigf(float x){ return RCPF(1.0f + __expf(-x)); }
__device__ __forceinline__ float tanh_fast(float x){
  float ax = fabsf(x);
  float e = __expf(-2.0f*ax);
  float t = (1.0f - e) * RCPF(1.0f + e);
  return x >= 0.0f ? t : -t;
}
__device__ __forceinline__ float dot2(f16x2 a, f16x2 b, float c){
#if __has_builtin(__builtin_amdgcn_fdot2)
  return __builtin_amdgcn_fdot2(a, b, c, false);
#else
  return c + (float)a.x*(float)b.x + (float)a.y*(float)b.y;
#endif
}
// relaxed agent-scope atomics: loads bypass caches to the coherence point
// (proven by round-1 spin); publishes use atomic-swap RMWs which execute AT
// the coherence point (no reliance on store write-through semantics).
__device__ __forceinline__ u64 aload64(const u64* p){
  return __hip_atomic_load(p, __ATOMIC_RELAXED, __HIP_MEMORY_SCOPE_AGENT);
}
__device__ __forceinline__ void apub64(u64* p, u64 v){
  (void)__hip_atomic_exchange(p, v, __ATOMIC_RELAXED, __HIP_MEMORY_SCOPE_AGENT);
}
__device__ __forceinline__ unsigned aload32(const unsigned* p){
  return __hip_atomic_load(p, __ATOMIC_RELAXED, __HIP_MEMORY_SCOPE_AGENT);
}
__device__ __forceinline__ void apub32(unsigned* p, unsigned v){
  (void)__hip_atomic_exchange(p, v, __ATOMIC_RELAXED, __HIP_MEMORY_SCOPE_AGENT);
}

// ---------------- gather x = [emb[shifted], emb[parent]] as f16 ----------------
__global__ __launch_bounds__(256) void gather_x(
    const float* __restrict__ emb, const int* __restrict__ act,
    const int* __restrict__ par, f16* __restrict__ X)
{
  const int t = blockIdx.x, lid = threadIdx.x;
  const int ia = (t == 0) ? 0 : (act[t-1] + 1);
  const int ip = par[t] + 1;
  const int half = lid >> 7;
  const int k = (lid & 127) << 2;
  const float* src = emb + (size_t)(half ? ip : ia) * 512 + k;
  float4 v = *(const float4*)src;
  f16x4 o; o.x=(f16)v.x; o.y=(f16)v.y; o.z=(f16)v.z; o.w=(f16)v.w;
  *(f16x4*)&X[(size_t)t*1024 + (half<<9) + k] = o;
}

// ---------------- fp32 -> f16 convert ----------------
__global__ __launch_bounds__(256) void cvt_k(const float* __restrict__ in,
                                             f16* __restrict__ out, int n)
{
  const int i = (blockIdx.x*256 + threadIdx.x) << 2;
  if (i >= n) return;
  float4 v = *(const float4*)&in[i];
  f16x4 o; o.x=(f16)v.x; o.y=(f16)v.y; o.z=(f16)v.z; o.w=(f16)v.w;
  *(f16x4*)&out[i] = o;
}

// ---------------- per-call init: zero flags, seed tagged h(-1) cells ----------------
__global__ __launch_bounds__(256) void init_ctrl(const float* __restrict__ init, char* ws)
{
  const int lid = threadIdx.x;
  unsigned* flg = (unsigned*)(ws + H0FLG_OFF);
  for (int i = lid; i < 1024; i += 256) flg[i] = 0;
  u64* hb0 = (u64*)(ws + HBUF0_OFF);
  u64* hb1 = (u64*)(ws + HBUF1_OFF);
  F2U a; a.f.x=(f16)init[2*lid];     a.f.y=(f16)init[2*lid+1];
  F2U c; c.f.x=(f16)init[512+2*lid]; c.f.y=(f16)init[512+2*lid+1];
  hb0[256 + lid] = (u64)a.u;   // buf parity 1, tag 0
  hb1[256 + lid] = (u64)c.u;   // buf parity 1, tag 0
}

// ---------------- f16 MFMA GEMM: C[M,N] = A[M,K] @ B[N,K]^T + bias ----------------
template<typename OutT>
__global__ __launch_bounds__(256) void gemm_f16(
    const f16* __restrict__ A, const f16* __restrict__ B,
    const float* __restrict__ bias, OutT* __restrict__ C,
    int M, int N, int K)
{
  __shared__ __align__(16) f16 At[4][128][8];
  __shared__ __align__(16) f16 Bt[4][128][8];
  const int lid = threadIdx.x;
  const int mtiles = M >> 7;
  const int bm = blockIdx.x % mtiles;
  const int bn = blockIdx.x / mtiles;
  const int m0 = bm << 7, n0 = bn << 7;
  const int lane = lid & 63, w = lid >> 6;
  const int wm = (w >> 1) << 6, wn = (w & 1) << 6;
  f32x4 acc[4][4] = {};
  const int nk = K >> 5;
  const int row1 = lid >> 2, j1 = lid & 3;
  for (int kt = 0; kt < nk; ++kt){
    const int kb = kt << 5;
    *(f16x8*)&At[j1][row1][0]    = *(const f16x8*)&A[(size_t)(m0+row1)*K    + kb + j1*8];
    *(f16x8*)&At[j1][row1+64][0] = *(const f16x8*)&A[(size_t)(m0+row1+64)*K + kb + j1*8];
    *(f16x8*)&Bt[j1][row1][0]    = *(const f16x8*)&B[(size_t)(n0+row1)*K    + kb + j1*8];
    *(f16x8*)&Bt[j1][row1+64][0] = *(const f16x8*)&B[(size_t)(n0+row1+64)*K + kb + j1*8];
    __syncthreads();
    const int kc = lane >> 4, rr = lane & 15;
    f16x8 aF[4], bF[4];
    #pragma unroll
    for (int m=0;m<4;m++) aF[m] = *(const f16x8*)&At[kc][wm + m*16 + rr][0];
    #pragma unroll
    for (int n=0;n<4;n++) bF[n] = *(const f16x8*)&Bt[kc][wn + n*16 + rr][0];
    #pragma unroll
    for (int m=0;m<4;m++)
      #pragma unroll
      for (int n=0;n<4;n++)
        acc[m][n] = __builtin_amdgcn_mfma_f32_16x16x32_f16(aF[m], bF[n], acc[m][n], 0,0,0);
    __syncthreads();
  }
  const int rr = lane & 15, rg = lane >> 4;
  #pragma unroll
  for (int n=0;n<4;n++){
    const int gcol = n0 + wn + n*16 + rr;
    const float bv = bias[gcol];
    #pragma unroll
    for (int m=0;m<4;m++){
      #pragma unroll
      for (int r=0;r<4;r++){
        const int grow = m0 + wm + m*16 + rg*4 + r;
        C[(size_t)grow*N + gcol] = (OutT)(acc[m][n][r] + bv);
      }
    }
  }
}

// ---------------- two decoupled tagged rings (fused 2-layer GRU scan) ----------------
// Blocks 0..7  = ring0 (layer0): 64 rows each, 4 thr/row, Whh0 in VGPRs.
//   Step q: poll peers' tagged cells (tag==q), compute h0[q], publish tagged
//   cells (tag q+1), stream h0seq data + per-block progress flag for ring1.
// Blocks 8..23 = ring1 (layer1): 32 rows each, 8 thr/row, Wih1+Whh1 in VGPRs.
//   Step t: wait flags>=t+1 then read h0seq[t]; poll own ring's tagged cells
//   (tag==t) for h1[t-1]; compute h1[t]; publish tagged cells + plain h1seq.
// No fences, no barriers: every shared datum rides in an 8B atomic cell
// whose tag validates it. Double-buffered cells are reuse-safe by induction.
__global__ __launch_bounds__(256, 1) void scan_rings(
    const float* __restrict__ Whh0, const float* __restrict__ bhh0,
    const float* __restrict__ Wih1, const float* __restrict__ bih1,
    const float* __restrict__ Whh1, const float* __restrict__ bhh1,
    const float* __restrict__ init, const f16* __restrict__ xi0,
    char* ws)
{
  const int lid = threadIdx.x;
  unsigned* h0seq = (unsigned*)(ws + H0SEQ_OFF);
  unsigned* flg   = (unsigned*)(ws + H0FLG_OFF);
  f16x2*    h1seq = (f16x2*)(ws + H1SEQ_OFF);
  u64* hb0 = (u64*)(ws + HBUF0_OFF);
  u64* hb1 = (u64*)(ws + HBUF1_OFF);
  __shared__ f16x2 hx[256];
  __shared__ f16x2 hh[256];

  if (blockIdx.x < 8){
    // ================= ring0: layer 0 =================
    const int b = blockIdx.x;
    const int ksub = lid & 3, row = (b << 6) + (lid >> 2);
    const bool owner = (ksub == 0);
    f16x2 wr[64], wz[64], wn[64];
    #pragma unroll
    for (int i=0;i<64;i++){
      const int k0 = (ksub + (i<<2)) << 1;
      float2 a = *(const float2*)&Whh0[(size_t)row*512         + k0];
      float2 bb= *(const float2*)&Whh0[(size_t)(512+row)*512   + k0];
      float2 c = *(const float2*)&Whh0[(size_t)(1024+row)*512  + k0];
      wr[i].x=(f16)a.x;  wr[i].y=(f16)a.y;
      wz[i].x=(f16)bb.x; wz[i].y=(f16)bb.y;
      wn[i].x=(f16)c.x;  wn[i].y=(f16)c.y;
    }
    float bhr=0.f, bhz=0.f, bhn=0.f;
    if (owner){ bhr=bhh0[row]; bhz=bhh0[512+row]; bhn=bhh0[1024+row]; }

    for (int q=0; q<S_LEN; ++q){
      float xr=0.f, xz=0.f, xn=0.f;
      if (owner){                      // immutable input gates (plain cached loads)
        const f16* xp = xi0 + (size_t)q*1536;
        xr=(float)xp[row]; xz=(float)xp[512+row]; xn=(float)xp[1024+row];
      }
      // poll peers' h0[q-1]: cell lid of buf[(q-1)&1], expect tag==q
      {
        u64* src = hb0 + ((q+1)&1)*256 + lid;
        u64 cell; int it=0;
        for(;;){ cell = aload64(src);
                 if ((unsigned)(cell>>32) == (unsigned)q) break;
                 if (++it > CAP) break; }
        F2U cu; cu.u = (unsigned)cell; hx[lid] = cu.f;
      }
      __syncthreads();
      float ar=0.f, az=0.f, an=0.f;
      #pragma unroll
      for (int i=0;i<64;i++){
        f16x2 hv = hx[ksub + (i<<2)];
        ar = dot2(wr[i], hv, ar); az = dot2(wz[i], hv, az); an = dot2(wn[i], hv, an);
      }
      ar += __shfl_xor(ar,1); ar += __shfl_xor(ar,2);
      az += __shfl_xor(az,1); az += __shfl_xor(az,2);
      an += __shfl_xor(an,1); an += __shfl_xor(an,2);
      float hnew = 0.f;
      if (owner){
        float r  = sigf(xr + ar + bhr);
        float z  = sigf(xz + az + bhz);
        float nl = tanh_fast(xn + r*(an + bhn));
        hnew = (1.0f - z)*nl + z*(float)hx[row>>1][row&1];
      }
      float hp = __shfl(hnew, (lid & 192) + ((lid+4) & 63));
      if ((lid & 7) == 0){             // pair (row, row+1) -> one cell
        F2U pr; pr.f.x=(f16)hnew; pr.f.y=(f16)hp;
        const int j = (b<<5) + (lid>>3);
        apub64(&hb0[(q&1)*256 + j], ((u64)(unsigned)(q+1)<<32) | (u64)pr.u);
        apub32(&h0seq[(size_t)q*256 + j], pr.u);
      }
      __syncthreads();                 // all waves' publishes drained (waitcnt before barrier)
      if (lid == 0) apub32(&flg[b*32], (unsigned)(q+1));
    }
  } else {
    // ================= ring1: layer 1 (fused W_ih1 + W_hh1) =================
    const int u = blockIdx.x - 8;
    const int ksub = lid & 7, rowl = lid >> 3, row = (u << 5) + rowl;
    const bool owner = (ksub == 0);
    f16x2 ur[32], uz[32], un[32], vr[32], vz[32], vn[32];
    #pragma unroll
    for (int i=0;i<32;i++){
      const int k0 = (ksub + (i<<3)) << 1;
      float2 a = *(const float2*)&Wih1[(size_t)row*512        + k0];
      float2 bb= *(const float2*)&Wih1[(size_t)(512+row)*512  + k0];
      float2 c = *(const float2*)&Wih1[(size_t)(1024+row)*512 + k0];
      float2 d = *(const float2*)&Whh1[(size_t)row*512        + k0];
      float2 e = *(const float2*)&Whh1[(size_t)(512+row)*512  + k0];
      float2 f = *(const float2*)&Whh1[(size_t)(1024+row)*512 + k0];
      ur[i].x=(f16)a.x;  ur[i].y=(f16)a.y;
      uz[i].x=(f16)bb.x; uz[i].y=(f16)bb.y;
      un[i].x=(f16)c.x;  un[i].y=(f16)c.y;
      vr[i].x=(f16)d.x;  vr[i].y=(f16)d.y;
      vz[i].x=(f16)e.x;  vz[i].y=(f16)e.y;
      vn[i].x=(f16)f.x;  vn[i].y=(f16)f.y;
    }
    float bir=0.f,biz=0.f,bin=0.f, bhr=0.f,bhz=0.f,bhn=0.f;
    if (owner){
      bir=bih1[row]; biz=bih1[512+row]; bin=bih1[1024+row];
      bhr=bhh1[row]; bhz=bhh1[512+row]; bhn=bhh1[1024+row];
    }

    for (int t=0; t<S_LEN; ++t){
      // wait h0[t] available (one-way flags, monotone within call), then load
      {
        unsigned* fp = &flg[(lid>>5)*32];
        int it=0;
        while (aload32(fp) < (unsigned)(t+1)) { if (++it > CAP) break; }
        F2U xc; xc.u = aload32(&h0seq[(size_t)t*256 + lid]);
        hx[lid] = xc.f;
      }
      // poll own ring's h1[t-1]: expect tag==t
      {
        u64* src = hb1 + ((t+1)&1)*256 + lid;
        u64 cell; int it=0;
        for(;;){ cell = aload64(src);
                 if ((unsigned)(cell>>32) == (unsigned)t) break;
                 if (++it > CAP) break; }
        F2U hc; hc.u = (unsigned)cell; hh[lid] = hc.f;
      }
      __syncthreads();
      float ir=0.f, iz=0.f, in_=0.f, hr=0.f, hz=0.f, hn=0.f;
      #pragma unroll
      for (int i=0;i<32;i++){
        f16x2 xv = hx[ksub + (i<<3)];
        f16x2 hv = hh[ksub + (i<<3)];
        ir = dot2(ur[i], xv, ir); iz = dot2(uz[i], xv, iz); in_ = dot2(un[i], xv, in_);
        hr = dot2(vr[i], hv, hr); hz = dot2(vz[i], hv, hz); hn  = dot2(vn[i], hv, hn);
      }
      #pragma unroll
      for (int d=1; d<8; d<<=1){
        ir += __shfl_xor(ir,d); iz += __shfl_xor(iz,d); in_ += __shfl_xor(in_,d);
        hr += __shfl_xor(hr,d); hz += __shfl_xor(hz,d); hn  += __shfl_xor(hn,d);
      }
      float hnew = 0.f;
      if (owner){
        float r  = sigf(ir + bir + hr + bhr);
        float z  = sigf(iz + biz + hz + bhz);
        float nl = tanh_fast(in_ + bin + r*(hn + bhn));
        hnew = (1.0f - z)*nl + z*(float)hh[row>>1][row&1];
      }
      float hp = __shfl(hnew, (lid & 192) + ((lid+8) & 63));
      if ((lid & 15) == 0){            // pair (row, row+1) -> one cell
        F2U pr; pr.f.x=(f16)hnew; pr.f.y=(f16)hp;
        const int j = (u<<4) + (lid>>4);
        apub64(&hb1[(t&1)*256 + j], ((u64)(unsigned)(t+1)<<32) | (u64)pr.u);
        h1seq[(size_t)t*256 + j] = pr.f;   // plain store; visible after kernel end
      }
      __syncthreads();                 // protect hx/hh from next step's staging
    }
  }
}

// ---------------- row-wise log_softmax over 2048, in place ----------------
__global__ __launch_bounds__(256) void logsoftmax_k(float* __restrict__ lp)
{
  const int t = blockIdx.x, lid = threadIdx.x;
  float* row = lp + (size_t)t*2048;
  float4 a = ((const float4*)row)[lid*2];
  float4 b = ((const float4*)row)[lid*2+1];
  float m = fmaxf(fmaxf(fmaxf(a.x,a.y),fmaxf(a.z,a.w)),
                  fmaxf(fmaxf(b.x,b.y),fmaxf(b.z,b.w)));
  #pragma unroll
  for (int off=1; off<64; off<<=1) m = fmaxf(m, __shfl_xor(m, off));
  __shared__ float redm[4], reds[4];
  const int lane = lid & 63, wvi = lid >> 6;
  if (lane==0) redm[wvi] = m;
  __syncthreads();
  m = fmaxf(fmaxf(redm[0],redm[1]), fmaxf(redm[2],redm[3]));
  float s = __expf(a.x-m)+__expf(a.y-m)+__expf(a.z-m)+__expf(a.w-m)
          + __expf(b.x-m)+__expf(b.y-m)+__expf(b.z-m)+__expf(b.w-m);
  #pragma unroll
  for (int off=1; off<64; off<<=1) s += __shfl_xor(s, off);
  if (lane==0) reds[wvi] = s;
  __syncthreads();
  s = reds[0]+reds[1]+reds[2]+reds[3];
  const float lg = m + __logf(s);
  a.x-=lg; a.y-=lg; a.z-=lg; a.w-=lg;
  b.x-=lg; b.y-=lg; b.z-=lg; b.w-=lg;
  ((float4*)row)[lid*2]   = a;
  ((float4*)row)[lid*2+1] = b;
}

// ---------------- values head: one wave per timestep ----------------
__global__ __launch_bounds__(256) void values_k(
    const f16* __restrict__ h1, const float* __restrict__ vW,
    const float* __restrict__ vb, float* __restrict__ outv, int S)
{
  const int gt = (int)((blockIdx.x*256 + threadIdx.x) >> 6);
  if (gt >= S) return;
  const int lane = threadIdx.x & 63;
  const f16* rowp = h1 + (size_t)gt*512;
  float s = 0.f;
  #pragma unroll
  for (int j=0;j<8;j++){
    const int k = lane + (j<<6);
    s += (float)rowp[k] * vW[k];
  }
  #pragma unroll
  for (int off=32; off; off>>=1) s += __shfl_down(s, off);
  if (lane==0) outv[gt] = s + vb[0];
}

extern "C" void kernel_launch(void* const* d_in, const int* in_sizes, int n_in,
                              void* d_out, int out_size, void* d_ws, size_t ws_size,
                              hipStream_t stream) {
  const float* init = (const float*)d_in[0];
  const float* emb  = (const float*)d_in[1];
  const float* Wih0 = (const float*)d_in[2];
  const float* Whh0 = (const float*)d_in[3];
  const float* bih0 = (const float*)d_in[4];
  const float* bhh0 = (const float*)d_in[5];
  const float* Wih1 = (const float*)d_in[6];
  const float* Whh1 = (const float*)d_in[7];
  const float* bih1 = (const float*)d_in[8];
  const float* bhh1 = (const float*)d_in[9];
  const float* actW = (const float*)d_in[10];
  const float* actb = (const float*)d_in[11];
  const float* valW = (const float*)d_in[12];
  const float* valb = (const float*)d_in[13];
  const int*   acts = (const int*)d_in[14];
  const int*   pars = (const int*)d_in[15];
  float* out = (float*)d_out;
  char*  w   = (char*)d_ws;

  f16* h1seq = (f16*)(w + H1SEQ_OFF);
  f16* actWh = (f16*)(w + ACTW_OFF);
  f16* Wih0h = (f16*)(w + WIH0_OFF);
  // xi0 f16 [S,1536] (48MB) and X f16 [S,1024] (32MB) both live in d_out,
  // dead before the logits GEMM overwrites it.
  f16* xi0 = (f16*)d_out;
  f16* X   = (f16*)((char*)d_out + 48u*1024*1024);

  gather_x<<<S_LEN, 256, 0, stream>>>(emb, acts, pars, X);
  cvt_k<<<1536, 256, 0, stream>>>(Wih0, Wih0h, 1536*1024);
  cvt_k<<<1024, 256, 0, stream>>>(actW, actWh, 2048*512);
  init_ctrl<<<1, 256, 0, stream>>>(init, w);

  // xi0 = X @ W_ih0^T + b_ih0   [S,1536]
  gemm_f16<f16><<<128*12, 256, 0, stream>>>(X, Wih0h, bih0, xi0, S_LEN, 1536, 1024);

  // fused two-layer scan: two decoupled tagged rings
  scan_rings<<<24, 256, 0, stream>>>(Whh0, bhh0, Wih1, bih1, Whh1, bhh1,
                                     init, xi0, w);

  // logits = h1seq @ action_W^T + action_b -> d_out, then log_softmax in place
  gemm_f16<float><<<128*16, 256, 0, stream>>>(h1seq, actWh, actb, out, S_LEN, NRULES, 512);
  logsoftmax_k<<<S_LEN, 256, 0, stream>>>(out);
  values_k<<<S_LEN/4, 256, 0, stream>>>(h1seq, valW, valb, out + (size_t)S_LEN*NRULES, S_LEN);
}

// Round 6
// 34224.106 us; speedup vs baseline: 2.9211x; 1.0293x over previous
//
#include <hip/hip_runtime.h>
#include <hip/hip_bf16.h>
#include <hip/hip_fp16.h>

typedef _Float16 f16;
typedef _Float16 f16x2 __attribute__((ext_vector_type(2)));
typedef _Float16 f16x4 __attribute__((ext_vector_type(4)));
typedef _Float16 f16x8 __attribute__((ext_vector_type(8)));
typedef float f32x4 __attribute__((ext_vector_type(4)));
typedef unsigned long long u64;

#define S_LEN 16384
#define NRULES 2048
#define CAP 2000000   // spin cap: converts any protocol failure into bounded abort

// ---- ws layout (bytes) ----
#define H1SEQ_OFF 0u                    // 16 MB f16 [S][512]
#define ACTW_OFF  (16u*1024*1024)       // 2 MB f16 action_W
#define WIH0_OFF  (18u*1024*1024)       // 3 MB f16 W_ih0
#define HBUF0_OFF (21u*1024*1024)       // 2*256 u64 tagged cells (4 KB)
#define HBUF1_OFF (21u*1024*1024+8192)  // 2*256 u64 tagged cells (4 KB)
// d_out overlay: [0,48M) xi0 f16 [S,1536]; [48M,80M) X f16 [S,1024];
//                [80M,112M) h0seq tagged u64 [S][256] (memset to 0 per call)

#if __has_builtin(__builtin_amdgcn_rcpf)
#define RCPF(x) __builtin_amdgcn_rcpf(x)
#else
#define RCPF(x) (1.0f/(x))
#endif

union F2U { f16x2 f; unsigned u; };

__device__ __forceinline__ float sigf(float x){ return RCPF(1.0f + __expf(-x)); }
__device__ __forceinline__ float tanh_fast(float x){
  float ax = fabsf(x);
  float e = __expf(-2.0f*ax);
  float t = (1.0f - e) * RCPF(1.0f + e);
  return x >= 0.0f ? t : -t;
}
__device__ __forceinline__ float dot2(f16x2 a, f16x2 b, float c){
#if __has_builtin(__builtin_amdgcn_fdot2)
  return __builtin_amdgcn_fdot2(a, b, c, false);
#else
  return c + (float)a.x*(float)b.x + (float)a.y*(float)b.y;
#endif
}
// relaxed agent-scope atomics (round-5-proven primitives)
__device__ __forceinline__ u64 aload64(const u64* p){
  return __hip_atomic_load(p, __ATOMIC_RELAXED, __HIP_MEMORY_SCOPE_AGENT);
}
__device__ __forceinline__ void apub64(u64* p, u64 v){
  (void)__hip_atomic_exchange(p, v, __ATOMIC_RELAXED, __HIP_MEMORY_SCOPE_AGENT);
}

// ---------------- gather x = [emb[shifted], emb[parent]] as f16 ----------------
__global__ __launch_bounds__(256) void gather_x(
    const float* __restrict__ emb, const int* __restrict__ act,
    const int* __restrict__ par, f16* __restrict__ X)
{
  const int t = blockIdx.x, lid = threadIdx.x;
  const int ia = (t == 0) ? 0 : (act[t-1] + 1);
  const int ip = par[t] + 1;
  const int half = lid >> 7;
  const int k = (lid & 127) << 2;
  const float* src = emb + (size_t)(half ? ip : ia) * 512 + k;
  float4 v = *(const float4*)src;
  f16x4 o; o.x=(f16)v.x; o.y=(f16)v.y; o.z=(f16)v.z; o.w=(f16)v.w;
  *(f16x4*)&X[(size_t)t*1024 + (half<<9) + k] = o;
}

// ---------------- fp32 -> f16 convert ----------------
__global__ __launch_bounds__(256) void cvt_k(const float* __restrict__ in,
                                             f16* __restrict__ out, int n)
{
  const int i = (blockIdx.x*256 + threadIdx.x) << 2;
  if (i >= n) return;
  float4 v = *(const float4*)&in[i];
  f16x4 o; o.x=(f16)v.x; o.y=(f16)v.y; o.z=(f16)v.z; o.w=(f16)v.w;
  *(f16x4*)&out[i] = o;
}

// ---- per-call init: seed tagged h(-1) cells, invalidate both parities ----
__global__ __launch_bounds__(256) void init_ctrl(const float* __restrict__ init, char* ws)
{
  const int lid = threadIdx.x;
  u64* hb0 = (u64*)(ws + HBUF0_OFF);
  u64* hb1 = (u64*)(ws + HBUF1_OFF);
  F2U a; a.f.x=(f16)init[2*lid];     a.f.y=(f16)init[2*lid+1];
  F2U c; c.f.x=(f16)init[512+2*lid]; c.f.y=(f16)init[512+2*lid+1];
  const u64 inval = (u64)0xF0000000u << 32;   // tag never matched
  hb0[lid]       = inval;
  hb0[256 + lid] = (u64)a.u;   // parity 1, tag 0 = h0 init
  hb1[lid]       = inval;
  hb1[256 + lid] = (u64)c.u;   // parity 1, tag 0 = h1 init
}

// ---------------- f16 MFMA GEMM: C[M,N] = A[M,K] @ B[N,K]^T + bias ----------------
template<typename OutT>
__global__ __launch_bounds__(256) void gemm_f16(
    const f16* __restrict__ A, const f16* __restrict__ B,
    const float* __restrict__ bias, OutT* __restrict__ C,
    int M, int N, int K)
{
  __shared__ __align__(16) f16 At[4][128][8];
  __shared__ __align__(16) f16 Bt[4][128][8];
  const int lid = threadIdx.x;
  const int mtiles = M >> 7;
  const int bm = blockIdx.x % mtiles;
  const int bn = blockIdx.x / mtiles;
  const int m0 = bm << 7, n0 = bn << 7;
  const int lane = lid & 63, w = lid >> 6;
  const int wm = (w >> 1) << 6, wn = (w & 1) << 6;
  f32x4 acc[4][4] = {};
  const int nk = K >> 5;
  const int row1 = lid >> 2, j1 = lid & 3;
  for (int kt = 0; kt < nk; ++kt){
    const int kb = kt << 5;
    *(f16x8*)&At[j1][row1][0]    = *(const f16x8*)&A[(size_t)(m0+row1)*K    + kb + j1*8];
    *(f16x8*)&At[j1][row1+64][0] = *(const f16x8*)&A[(size_t)(m0+row1+64)*K + kb + j1*8];
    *(f16x8*)&Bt[j1][row1][0]    = *(const f16x8*)&B[(size_t)(n0+row1)*K    + kb + j1*8];
    *(f16x8*)&Bt[j1][row1+64][0] = *(const f16x8*)&B[(size_t)(n0+row1+64)*K + kb + j1*8];
    __syncthreads();
    const int kc = lane >> 4, rr = lane & 15;
    f16x8 aF[4], bF[4];
    #pragma unroll
    for (int m=0;m<4;m++) aF[m] = *(const f16x8*)&At[kc][wm + m*16 + rr][0];
    #pragma unroll
    for (int n=0;n<4;n++) bF[n] = *(const f16x8*)&Bt[kc][wn + n*16 + rr][0];
    #pragma unroll
    for (int m=0;m<4;m++)
      #pragma unroll
      for (int n=0;n<4;n++)
        acc[m][n] = __builtin_amdgcn_mfma_f32_16x16x32_f16(aF[m], bF[n], acc[m][n], 0,0,0);
    __syncthreads();
  }
  const int rr = lane & 15, rg = lane >> 4;
  #pragma unroll
  for (int n=0;n<4;n++){
    const int gcol = n0 + wn + n*16 + rr;
    const float bv = bias[gcol];
    #pragma unroll
    for (int m=0;m<4;m++){
      #pragma unroll
      for (int r=0;r<4;r++){
        const int grow = m0 + wm + m*16 + rg*4 + r;
        C[(size_t)grow*N + gcol] = (OutT)(acc[m][n][r] + bv);
      }
    }
  }
}

// ---------------- two decoupled tagged rings (fused 2-layer GRU scan) ----------------
// Blocks 0..7  = ring0 (layer0), 64 rows each, 4 thr/row, Whh0 in VGPRs.
//   Step q: poll hb0 (tag==q) -> h0[q-1]; compute h0[q]; publish hb0 cells
//   (tag q+1) AND write-once tagged h0seq[q] cells (tag q+1).
// Blocks 8..23 = ring1 (layer1), 32 rows each, 8 thr/row, Wih1+Whh1 in VGPRs.
//   Step t: DUAL-poll (both loads in flight each iteration): h0seq[t]
//   (tag==t+1) and hb1 (tag==t) -> compute h1[t]; publish hb1 + plain h1seq.
// Monotone tags + write-once h0seq + per-call invalidation: no fences needed.
__global__ __launch_bounds__(256, 1) void scan_rings(
    const float* __restrict__ Whh0, const float* __restrict__ bhh0,
    const float* __restrict__ Wih1, const float* __restrict__ bih1,
    const float* __restrict__ Whh1, const float* __restrict__ bhh1,
    const float* __restrict__ init, const f16* __restrict__ xi0,
    u64* __restrict__ h0seq, char* ws)
{
  const int lid = threadIdx.x;
  f16x2* h1seq = (f16x2*)(ws + H1SEQ_OFF);
  u64* hb0 = (u64*)(ws + HBUF0_OFF);
  u64* hb1 = (u64*)(ws + HBUF1_OFF);
  __shared__ f16x2 hx[256];
  __shared__ f16x2 hh[256];

  if (blockIdx.x < 8){
    // ================= ring0: layer 0 =================
    const int b = blockIdx.x;
    const int ksub = lid & 3, row = (b << 6) + (lid >> 2);
    const bool owner = (ksub == 0);
    f16x2 wr[64], wz[64], wn[64];
    #pragma unroll
    for (int i=0;i<64;i++){
      const int k0 = (ksub + (i<<2)) << 1;
      float2 a = *(const float2*)&Whh0[(size_t)row*512         + k0];
      float2 bb= *(const float2*)&Whh0[(size_t)(512+row)*512   + k0];
      float2 c = *(const float2*)&Whh0[(size_t)(1024+row)*512  + k0];
      wr[i].x=(f16)a.x;  wr[i].y=(f16)a.y;
      wz[i].x=(f16)bb.x; wz[i].y=(f16)bb.y;
      wn[i].x=(f16)c.x;  wn[i].y=(f16)c.y;
    }
    float bhr=0.f, bhz=0.f, bhn=0.f;
    if (owner){ bhr=bhh0[row]; bhz=bhh0[512+row]; bhn=bhh0[1024+row]; }

    for (int q=0; q<S_LEN; ++q){
      float xr=0.f, xz=0.f, xn=0.f;
      if (owner){                      // immutable input gates (plain cached loads)
        const f16* xp = xi0 + (size_t)q*1536;
        xr=(float)xp[row]; xz=(float)xp[512+row]; xn=(float)xp[1024+row];
      }
      // poll peers' h0[q-1]: cell lid of buf parity (q+1)&1, expect tag==q
      {
        u64* src = hb0 + ((q+1)&1)*256 + lid;
        u64 cell; int it=0;
        for(;;){ cell = aload64(src);
                 if ((unsigned)(cell>>32) == (unsigned)q) break;
                 if (++it > CAP) break; }
        F2U cu; cu.u = (unsigned)cell; hx[lid] = cu.f;
      }
      __syncthreads();
      float ar=0.f, az=0.f, an=0.f;
      #pragma unroll
      for (int i=0;i<64;i++){
        f16x2 hv = hx[ksub + (i<<2)];
        ar = dot2(wr[i], hv, ar); az = dot2(wz[i], hv, az); an = dot2(wn[i], hv, an);
      }
      ar += __shfl_xor(ar,1); ar += __shfl_xor(ar,2);
      az += __shfl_xor(az,1); az += __shfl_xor(az,2);
      an += __shfl_xor(an,1); an += __shfl_xor(an,2);
      float hnew = 0.f;
      if (owner){
        float r  = sigf(xr + ar + bhr);
        float z  = sigf(xz + az + bhz);
        float nl = tanh_fast(xn + r*(an + bhn));
        hnew = (1.0f - z)*nl + z*(float)hx[row>>1][row&1];
      }
      float hp = __shfl(hnew, (lid & 192) + ((lid+4) & 63));
      if ((lid & 7) == 0){             // pair (row, row+1) -> one tagged cell
        F2U pr; pr.f.x=(f16)hnew; pr.f.y=(f16)hp;
        const int j = (b<<5) + (lid>>3);
        const u64 tagged = ((u64)(unsigned)(q+1)<<32) | (u64)pr.u;
        apub64(&hb0[(q&1)*256 + j], tagged);
        apub64(&h0seq[(size_t)q*256 + j], tagged);   // write-once, self-validating
      }
      __syncthreads();                 // protect hx before next step's staging
    }
  } else {
    // ================= ring1: layer 1 (fused W_ih1 + W_hh1) =================
    const int u = blockIdx.x - 8;
    const int ksub = lid & 7, row = (u << 5) + (lid >> 3);
    const bool owner = (ksub == 0);
    f16x2 ur[32], uz[32], un[32], vr[32], vz[32], vn[32];
    #pragma unroll
    for (int i=0;i<32;i++){
      const int k0 = (ksub + (i<<3)) << 1;
      float2 a = *(const float2*)&Wih1[(size_t)row*512        + k0];
      float2 bb= *(const float2*)&Wih1[(size_t)(512+row)*512  + k0];
      float2 c = *(const float2*)&Wih1[(size_t)(1024+row)*512 + k0];
      float2 d = *(const float2*)&Whh1[(size_t)row*512        + k0];
      float2 e = *(const float2*)&Whh1[(size_t)(512+row)*512  + k0];
      float2 f = *(const float2*)&Whh1[(size_t)(1024+row)*512 + k0];
      ur[i].x=(f16)a.x;  ur[i].y=(f16)a.y;
      uz[i].x=(f16)bb.x; uz[i].y=(f16)bb.y;
      un[i].x=(f16)c.x;  un[i].y=(f16)c.y;
      vr[i].x=(f16)d.x;  vr[i].y=(f16)d.y;
      vz[i].x=(f16)e.x;  vz[i].y=(f16)e.y;
      vn[i].x=(f16)f.x;  vn[i].y=(f16)f.y;
    }
    float bir=0.f,biz=0.f,bin=0.f, bhr=0.f,bhz=0.f,bhn=0.f;
    if (owner){
      bir=bih1[row]; biz=bih1[512+row]; bin=bih1[1024+row];
      bhr=bhh1[row]; bhz=bhh1[512+row]; bhn=bhh1[1024+row];
    }

    for (int t=0; t<S_LEN; ++t){
      // DUAL poll, both loads in flight per iteration (one roundtrip latency):
      //   h0seq[t*256+lid] expect tag t+1; hb1 parity (t+1)&1 expect tag t
      {
        const u64* pa = h0seq + (size_t)t*256 + lid;
        const u64* pb = hb1 + ((t+1)&1)*256 + lid;
        u64 ca, cb; int it=0;
        for(;;){
          ca = aload64(pa); cb = aload64(pb);
          if ((unsigned)(ca>>32) == (unsigned)(t+1) &&
              (unsigned)(cb>>32) == (unsigned)t) break;
          if (++it > CAP) break;
        }
        F2U xa; xa.u = (unsigned)ca; hx[lid] = xa.f;
        F2U hb; hb.u = (unsigned)cb; hh[lid] = hb.f;
      }
      __syncthreads();
      float ir=0.f, iz=0.f, in_=0.f, hr=0.f, hz=0.f, hn=0.f;
      #pragma unroll
      for (int i=0;i<32;i++){
        f16x2 xv = hx[ksub + (i<<3)];
        f16x2 hv = hh[ksub + (i<<3)];
        ir = dot2(ur[i], xv, ir); iz = dot2(uz[i], xv, iz); in_ = dot2(un[i], xv, in_);
        hr = dot2(vr[i], hv, hr); hz = dot2(vz[i], hv, hz); hn  = dot2(vn[i], hv, hn);
      }
      #pragma unroll
      for (int d=1; d<8; d<<=1){
        ir += __shfl_xor(ir,d); iz += __shfl_xor(iz,d); in_ += __shfl_xor(in_,d);
        hr += __shfl_xor(hr,d); hz += __shfl_xor(hz,d); hn  += __shfl_xor(hn,d);
      }
      float hnew = 0.f;
      if (owner){
        float r  = sigf(ir + bir + hr + bhr);
        float z  = sigf(iz + biz + hz + bhz);
        float nl = tanh_fast(in_ + bin + r*(hn + bhn));
        hnew = (1.0f - z)*nl + z*(float)hh[row>>1][row&1];
      }
      float hp = __shfl(hnew, (lid & 192) + ((lid+8) & 63));
      if ((lid & 15) == 0){            // pair (row, row+1) -> one cell
        F2U pr; pr.f.x=(f16)hnew; pr.f.y=(f16)hp;
        const int j = (u<<4) + (lid>>4);
        apub64(&hb1[(t&1)*256 + j], ((u64)(unsigned)(t+1)<<32) | (u64)pr.u);
        h1seq[(size_t)t*256 + j] = pr.f;   // plain store; visible after kernel end
      }
      __syncthreads();                 // protect hx/hh before next step's staging
    }
  }
}

// ---------------- row-wise log_softmax over 2048, in place ----------------
__global__ __launch_bounds__(256) void logsoftmax_k(float* __restrict__ lp)
{
  const int t = blockIdx.x, lid = threadIdx.x;
  float* row = lp + (size_t)t*2048;
  float4 a = ((const float4*)row)[lid*2];
  float4 b = ((const float4*)row)[lid*2+1];
  float m = fmaxf(fmaxf(fmaxf(a.x,a.y),fmaxf(a.z,a.w)),
                  fmaxf(fmaxf(b.x,b.y),fmaxf(b.z,b.w)));
  #pragma unroll
  for (int off=1; off<64; off<<=1) m = fmaxf(m, __shfl_xor(m, off));
  __shared__ float redm[4], reds[4];
  const int lane = lid & 63, wvi = lid >> 6;
  if (lane==0) redm[wvi] = m;
  __syncthreads();
  m = fmaxf(fmaxf(redm[0],redm[1]), fmaxf(redm[2],redm[3]));
  float s = __expf(a.x-m)+__expf(a.y-m)+__expf(a.z-m)+__expf(a.w-m)
          + __expf(b.x-m)+__expf(b.y-m)+__expf(b.z-m)+__expf(b.w-m);
  #pragma unroll
  for (int off=1; off<64; off<<=1) s += __shfl_xor(s, off);
  if (lane==0) reds[wvi] = s;
  __syncthreads();
  s = reds[0]+reds[1]+reds[2]+reds[3];
  const float lg = m + __logf(s);
  a.x-=lg; a.y-=lg; a.z-=lg; a.w-=lg;
  b.x-=lg; b.y-=lg; b.z-=lg; b.w-=lg;
  ((float4*)row)[lid*2]   = a;
  ((float4*)row)[lid*2+1] = b;
}

// ---------------- values head: one wave per timestep ----------------
__global__ __launch_bounds__(256) void values_k(
    const f16* __restrict__ h1, const float* __restrict__ vW,
    const float* __restrict__ vb, float* __restrict__ outv, int S)
{
  const int gt = (int)((blockIdx.x*256 + threadIdx.x) >> 6);
  if (gt >= S) return;
  const int lane = threadIdx.x & 63;
  const f16* rowp = h1 + (size_t)gt*512;
  float s = 0.f;
  #pragma unroll
  for (int j=0;j<8;j++){
    const int k = lane + (j<<6);
    s += (float)rowp[k] * vW[k];
  }
  #pragma unroll
  for (int off=32; off; off>>=1) s += __shfl_down(s, off);
  if (lane==0) outv[gt] = s + vb[0];
}

extern "C" void kernel_launch(void* const* d_in, const int* in_sizes, int n_in,
                              void* d_out, int out_size, void* d_ws, size_t ws_size,
                              hipStream_t stream) {
  const float* init = (const float*)d_in[0];
  const float* emb  = (const float*)d_in[1];
  const float* Wih0 = (const float*)d_in[2];
  const float* Whh0 = (const float*)d_in[3];
  const float* bih0 = (const float*)d_in[4];
  const float* bhh0 = (const float*)d_in[5];
  const float* Wih1 = (const float*)d_in[6];
  const float* Whh1 = (const float*)d_in[7];
  const float* bih1 = (const float*)d_in[8];
  const float* bhh1 = (const float*)d_in[9];
  const float* actW = (const float*)d_in[10];
  const float* actb = (const float*)d_in[11];
  const float* valW = (const float*)d_in[12];
  const float* valb = (const float*)d_in[13];
  const int*   acts = (const int*)d_in[14];
  const int*   pars = (const int*)d_in[15];
  float* out = (float*)d_out;
  char*  w   = (char*)d_ws;

  f16* h1seq = (f16*)(w + H1SEQ_OFF);
  f16* actWh = (f16*)(w + ACTW_OFF);
  f16* Wih0h = (f16*)(w + WIH0_OFF);
  // d_out overlays (all dead before the logits GEMM writes d_out):
  f16* xi0   = (f16*)d_out;                                  // [0,48M)
  f16* X     = (f16*)((char*)d_out + 48u*1024*1024);         // [48M,80M)
  u64* h0seq = (u64*)((char*)d_out + 80u*1024*1024);         // [80M,112M)

  // clear h0seq tags (stale tags from prior replay would short-circuit ring1)
  hipMemsetAsync(h0seq, 0, (size_t)S_LEN*256*8, stream);
  gather_x<<<S_LEN, 256, 0, stream>>>(emb, acts, pars, X);
  cvt_k<<<1536, 256, 0, stream>>>(Wih0, Wih0h, 1536*1024);
  cvt_k<<<1024, 256, 0, stream>>>(actW, actWh, 2048*512);
  init_ctrl<<<1, 256, 0, stream>>>(init, w);

  // xi0 = X @ W_ih0^T + b_ih0   [S,1536]
  gemm_f16<f16><<<128*12, 256, 0, stream>>>(X, Wih0h, bih0, xi0, S_LEN, 1536, 1024);

  // fused two-layer scan: two decoupled tagged rings
  scan_rings<<<24, 256, 0, stream>>>(Whh0, bhh0, Wih1, bih1, Whh1, bhh1,
                                     init, xi0, h0seq, w);

  // logits = h1seq @ action_W^T + action_b -> d_out, then log_softmax in place
  gemm_f16<float><<<128*16, 256, 0, stream>>>(h1seq, actWh, actb, out, S_LEN, NRULES, 512);
  logsoftmax_k<<<S_LEN, 256, 0, stream>>>(out);
  values_k<<<S_LEN/4, 256, 0, stream>>>(h1seq, valW, valb, out + (size_t)S_LEN*NRULES, S_LEN);
}

// Round 7
// 30430.786 us; speedup vs baseline: 3.2852x; 1.1247x over previous
//
#include <hip/hip_runtime.h>
#include <hip/hip_bf16.h>
#include <hip/hip_fp16.h>

typedef _Float16 f16;
typedef _Float16 f16x2 __attribute__((ext_vector_type(2)));
typedef _Float16 f16x4 __attribute__((ext_vector_type(4)));
typedef _Float16 f16x8 __attribute__((ext_vector_type(8)));
typedef float f32x4 __attribute__((ext_vector_type(4)));
typedef unsigned long long u64;

#define S_LEN 16384
#define NRULES 2048
#define CAP 2000000    // safecell spin cap: protocol failure -> bounded abort
#define FAST_TRIES 64  // bounded fastcell probe before sticky fallback

// ---- ws layout (bytes) ----
#define H1SEQ_OFF 0u                    // 16 MB f16 [S][512]
#define ACTW_OFF  (16u*1024*1024)       // 2 MB f16 action_W
#define WIH0_OFF  (18u*1024*1024)       // 3 MB f16 W_ih0
#define HB0F_OFF  (21u*1024*1024)           // 2*256 u64 fastcells ring0
#define HB0S_OFF  (21u*1024*1024 + 4096)    // 2*256 u64 safecells ring0
#define HB1F_OFF  (21u*1024*1024 + 8192)    // 2*256 u64 fastcells ring1
#define HB1S_OFF  (21u*1024*1024 + 12288)   // 2*256 u64 safecells ring1
// d_out overlay: [0,48M) xi0 f16 [S,1536]; [48M,80M) X f16 [S,1024];
//                [80M,112M) h0seq tagged u64 [S][256] (memset 0 per call)

#if __has_builtin(__builtin_amdgcn_rcpf)
#define RCPF(x) __builtin_amdgcn_rcpf(x)
#else
#define RCPF(x) (1.0f/(x))
#endif

union F2U { f16x2 f; unsigned u; };

__device__ __forceinline__ float sigf(float x){ return RCPF(1.0f + __expf(-x)); }
__device__ __forceinline__ float tanh_fast(float x){
  float ax = fabsf(x);
  float e = __expf(-2.0f*ax);
  float t = (1.0f - e) * RCPF(1.0f + e);
  return x >= 0.0f ? t : -t;
}
__device__ __forceinline__ float dot2(f16x2 a, f16x2 b, float c){
#if __has_builtin(__builtin_amdgcn_fdot2)
  return __builtin_amdgcn_fdot2(a, b, c, false);
#else
  return c + (float)a.x*(float)b.x + (float)a.y*(float)b.y;
#endif
}
// round-5/6-proven authoritative primitives (coherence-point):
__device__ __forceinline__ u64 aload64(const u64* p){
  return __hip_atomic_load(p, __ATOMIC_RELAXED, __HIP_MEMORY_SCOPE_AGENT);
}
__device__ __forceinline__ void apub64(u64* p, u64 v){
  (void)__hip_atomic_exchange(p, v, __ATOMIC_RELAXED, __HIP_MEMORY_SCOPE_AGENT);
}
// fast-path primitives (same-XCD L2): plain 8B store (L1 is write-through on
// CDNA -> lands in shared L2); sc0 load bypasses L1, served by L2.
__device__ __forceinline__ u64 load_sc0_u64(const u64* p){
  u64 v;
  asm volatile("global_load_dwordx2 %0, %1, off sc0\n\ts_waitcnt vmcnt(0)"
               : "=v"(v) : "v"(p) : "memory");
  return v;
}
__device__ __forceinline__ void store_u64(u64* p, u64 v){
  asm volatile("global_store_dwordx2 %0, %1, off"
               :: "v"(p), "v"(v) : "memory");
}

// ---------------- gather x = [emb[shifted], emb[parent]] as f16 ----------------
__global__ __launch_bounds__(256) void gather_x(
    const float* __restrict__ emb, const int* __restrict__ act,
    const int* __restrict__ par, f16* __restrict__ X)
{
  const int t = blockIdx.x, lid = threadIdx.x;
  const int ia = (t == 0) ? 0 : (act[t-1] + 1);
  const int ip = par[t] + 1;
  const int half = lid >> 7;
  const int k = (lid & 127) << 2;
  const float* src = emb + (size_t)(half ? ip : ia) * 512 + k;
  float4 v = *(const float4*)src;
  f16x4 o; o.x=(f16)v.x; o.y=(f16)v.y; o.z=(f16)v.z; o.w=(f16)v.w;
  *(f16x4*)&X[(size_t)t*1024 + (half<<9) + k] = o;
}

// ---------------- fp32 -> f16 convert ----------------
__global__ __launch_bounds__(256) void cvt_k(const float* __restrict__ in,
                                             f16* __restrict__ out, int n)
{
  const int i = (blockIdx.x*256 + threadIdx.x) << 2;
  if (i >= n) return;
  float4 v = *(const float4*)&in[i];
  f16x4 o; o.x=(f16)v.x; o.y=(f16)v.y; o.z=(f16)v.z; o.w=(f16)v.w;
  *(f16x4*)&out[i] = o;
}

// ---- per-call init: seed tagged h(-1) cells (fast+safe), invalidate parity0 ----
__global__ __launch_bounds__(256) void init_ctrl(const float* __restrict__ init, char* ws)
{
  const int lid = threadIdx.x;
  u64* f0 = (u64*)(ws + HB0F_OFF);
  u64* s0 = (u64*)(ws + HB0S_OFF);
  u64* f1 = (u64*)(ws + HB1F_OFF);
  u64* s1 = (u64*)(ws + HB1S_OFF);
  F2U a; a.f.x=(f16)init[2*lid];     a.f.y=(f16)init[2*lid+1];
  F2U c; c.f.x=(f16)init[512+2*lid]; c.f.y=(f16)init[512+2*lid+1];
  const u64 inval = (u64)0xF0000000u << 32;   // tag never matched
  const u64 sa = (u64)a.u, sc = (u64)c.u;     // parity 1, tag 0 seeds
  f0[lid] = inval; f0[256+lid] = sa;
  s0[lid] = inval; s0[256+lid] = sa;
  f1[lid] = inval; f1[256+lid] = sc;
  s1[lid] = inval; s1[256+lid] = sc;
}

// ---------------- f16 MFMA GEMM: C[M,N] = A[M,K] @ B[N,K]^T + bias ----------------
template<typename OutT>
__global__ __launch_bounds__(256) void gemm_f16(
    const f16* __restrict__ A, const f16* __restrict__ B,
    const float* __restrict__ bias, OutT* __restrict__ C,
    int M, int N, int K)
{
  __shared__ __align__(16) f16 At[4][128][8];
  __shared__ __align__(16) f16 Bt[4][128][8];
  const int lid = threadIdx.x;
  const int mtiles = M >> 7;
  const int bm = blockIdx.x % mtiles;
  const int bn = blockIdx.x / mtiles;
  const int m0 = bm << 7, n0 = bn << 7;
  const int lane = lid & 63, w = lid >> 6;
  const int wm = (w >> 1) << 6, wn = (w & 1) << 6;
  f32x4 acc[4][4] = {};
  const int nk = K >> 5;
  const int row1 = lid >> 2, j1 = lid & 3;
  for (int kt = 0; kt < nk; ++kt){
    const int kb = kt << 5;
    *(f16x8*)&At[j1][row1][0]    = *(const f16x8*)&A[(size_t)(m0+row1)*K    + kb + j1*8];
    *(f16x8*)&At[j1][row1+64][0] = *(const f16x8*)&A[(size_t)(m0+row1+64)*K + kb + j1*8];
    *(f16x8*)&Bt[j1][row1][0]    = *(const f16x8*)&B[(size_t)(n0+row1)*K    + kb + j1*8];
    *(f16x8*)&Bt[j1][row1+64][0] = *(const f16x8*)&B[(size_t)(n0+row1+64)*K + kb + j1*8];
    __syncthreads();
    const int kc = lane >> 4, rr = lane & 15;
    f16x8 aF[4], bF[4];
    #pragma unroll
    for (int m=0;m<4;m++) aF[m] = *(const f16x8*)&At[kc][wm + m*16 + rr][0];
    #pragma unroll
    for (int n=0;n<4;n++) bF[n] = *(const f16x8*)&Bt[kc][wn + n*16 + rr][0];
    #pragma unroll
    for (int m=0;m<4;m++)
      #pragma unroll
      for (int n=0;n<4;n++)
        acc[m][n] = __builtin_amdgcn_mfma_f32_16x16x32_f16(aF[m], bF[n], acc[m][n], 0,0,0);
    __syncthreads();
  }
  const int rr = lane & 15, rg = lane >> 4;
  #pragma unroll
  for (int n=0;n<4;n++){
    const int gcol = n0 + wn + n*16 + rr;
    const float bv = bias[gcol];
    #pragma unroll
    for (int m=0;m<4;m++){
      #pragma unroll
      for (int r=0;r<4;r++){
        const int grow = m0 + wm + m*16 + rg*4 + r;
        C[(size_t)grow*N + gcol] = (OutT)(acc[m][n][r] + bv);
      }
    }
  }
}

// -------- two tagged rings with same-XCD fast path + per-thread fallback --------
// grid=128. ring0 = blocks {0,8,..,56} (one XCD if dispatch round-robins),
// ring1 = blocks {1,9,..,121} (another XCD). Everyone else exits.
// Publish = fastcell plain store (L2, write-through L1) + safecell agent
// exchange (coherence point, authoritative). Poll = sc0 fastcell (bounded
// FAST_TRIES) then sticky per-thread fallback to safecell agent loads.
// Tags self-validate every cell; parity reuse safe by the r5/r6 induction.
__global__ __launch_bounds__(256, 1) void scan_rings(
    const float* __restrict__ Whh0, const float* __restrict__ bhh0,
    const float* __restrict__ Wih1, const float* __restrict__ bih1,
    const float* __restrict__ Whh1, const float* __restrict__ bhh1,
    const float* __restrict__ init, const f16* __restrict__ xi0,
    u64* __restrict__ h0seq, char* ws)
{
  const int lid = threadIdx.x;
  const int bid = blockIdx.x;
  f16x2* h1seq = (f16x2*)(ws + H1SEQ_OFF);
  u64* hb0f = (u64*)(ws + HB0F_OFF);
  u64* hb0s = (u64*)(ws + HB0S_OFF);
  u64* hb1f = (u64*)(ws + HB1F_OFF);
  u64* hb1s = (u64*)(ws + HB1S_OFF);
  __shared__ f16x2 hx[256];
  __shared__ f16x2 hh[256];

  const int lane7 = bid & 7, grp = bid >> 3;
  bool fast_ok = true;                 // per-thread sticky fast-path health

  if (lane7 == 0 && grp < 8){
    // ================= ring0: layer 0 =================
    const int b = grp;
    const int ksub = lid & 3, row = (b << 6) + (lid >> 2);
    const bool owner = (ksub == 0);
    f16x2 wr[64], wz[64], wn[64];
    #pragma unroll
    for (int i=0;i<64;i++){
      const int k0 = (ksub + (i<<2)) << 1;
      float2 a = *(const float2*)&Whh0[(size_t)row*512         + k0];
      float2 bb= *(const float2*)&Whh0[(size_t)(512+row)*512   + k0];
      float2 c = *(const float2*)&Whh0[(size_t)(1024+row)*512  + k0];
      wr[i].x=(f16)a.x;  wr[i].y=(f16)a.y;
      wz[i].x=(f16)bb.x; wz[i].y=(f16)bb.y;
      wn[i].x=(f16)c.x;  wn[i].y=(f16)c.y;
    }
    float bhr=0.f, bhz=0.f, bhn=0.f;
    if (owner){ bhr=bhh0[row]; bhz=bhh0[512+row]; bhn=bhh0[1024+row]; }

    for (int q=0; q<S_LEN; ++q){
      float xr=0.f, xz=0.f, xn=0.f;
      if (owner){                      // immutable input gates, issued pre-poll
        const f16* xp = xi0 + (size_t)q*1536;
        xr=(float)xp[row]; xz=(float)xp[512+row]; xn=(float)xp[1024+row];
      }
      {  // poll parity (q+1)&1, expect tag q
        const int par = (q+1)&1;
        const u64* pf = hb0f + par*256 + lid;
        const u64* ps = hb0s + par*256 + lid;
        u64 cell = 0; bool got = false;
        if (fast_ok){
          for (int k=0;k<FAST_TRIES;k++){
            u64 v = load_sc0_u64(pf);
            if ((unsigned)(v>>32) == (unsigned)q){ cell=v; got=true; break; }
          }
          if (!got) fast_ok = false;   // sticky: safecells from now on
        }
        if (!got){
          int it=0;
          for(;;){ u64 v = aload64(ps);
                   if ((unsigned)(v>>32) == (unsigned)q){ cell=v; break; }
                   if (++it > CAP){ cell=v; break; } }
        }
        F2U cu; cu.u = (unsigned)cell; hx[lid] = cu.f;
      }
      __syncthreads();
      float ar=0.f, az=0.f, an=0.f;
      #pragma unroll
      for (int i=0;i<64;i++){
        f16x2 hv = hx[ksub + (i<<2)];
        ar = dot2(wr[i], hv, ar); az = dot2(wz[i], hv, az); an = dot2(wn[i], hv, an);
      }
      ar += __shfl_xor(ar,1); ar += __shfl_xor(ar,2);
      az += __shfl_xor(az,1); az += __shfl_xor(az,2);
      an += __shfl_xor(an,1); an += __shfl_xor(an,2);
      float hnew = 0.f;
      if (owner){
        float r  = sigf(xr + ar + bhr);
        float z  = sigf(xz + az + bhz);
        float nl = tanh_fast(xn + r*(an + bhn));
        hnew = (1.0f - z)*nl + z*(float)hx[row>>1][row&1];
      }
      float hp = __shfl(hnew, (lid & 192) + ((lid+4) & 63));
      if ((lid & 7) == 0){             // pair (row,row+1) -> one tagged cell
        F2U pr; pr.f.x=(f16)hnew; pr.f.y=(f16)hp;
        const int j = (b<<5) + (lid>>3);
        const u64 tagged = ((u64)(unsigned)(q+1)<<32) | (u64)pr.u;
        store_u64(&hb0f[(q&1)*256 + j], tagged);     // fast (same-XCD L2)
        apub64(&hb0s[(q&1)*256 + j], tagged);        // authoritative
        apub64(&h0seq[(size_t)q*256 + j], tagged);   // for ring1 (cross-XCD)
      }
      __syncthreads();                 // drains publishes; protects hx
    }
  } else if (lane7 == 1 && grp < 16){
    // ================= ring1: layer 1 (fused W_ih1 + W_hh1) =================
    const int u = grp;
    const int ksub = lid & 7, row = (u << 5) + (lid >> 3);
    const bool owner = (ksub == 0);
    f16x2 ur[32], uz[32], un[32], vr[32], vz[32], vn[32];
    #pragma unroll
    for (int i=0;i<32;i++){
      const int k0 = (ksub + (i<<3)) << 1;
      float2 a = *(const float2*)&Wih1[(size_t)row*512        + k0];
      float2 bb= *(const float2*)&Wih1[(size_t)(512+row)*512  + k0];
      float2 c = *(const float2*)&Wih1[(size_t)(1024+row)*512 + k0];
      float2 d = *(const float2*)&Whh1[(size_t)row*512        + k0];
      float2 e = *(const float2*)&Whh1[(size_t)(512+row)*512  + k0];
      float2 f = *(const float2*)&Whh1[(size_t)(1024+row)*512 + k0];
      ur[i].x=(f16)a.x;  ur[i].y=(f16)a.y;
      uz[i].x=(f16)bb.x; uz[i].y=(f16)bb.y;
      un[i].x=(f16)c.x;  un[i].y=(f16)c.y;
      vr[i].x=(f16)d.x;  vr[i].y=(f16)d.y;
      vz[i].x=(f16)e.x;  vz[i].y=(f16)e.y;
      vn[i].x=(f16)f.x;  vn[i].y=(f16)f.y;
    }
    float bir=0.f,biz=0.f,bin=0.f, bhr=0.f,bhz=0.f,bhn=0.f;
    if (owner){
      bir=bih1[row]; biz=bih1[512+row]; bin=bih1[1024+row];
      bhr=bhh1[row]; bhz=bhh1[512+row]; bhn=bhh1[1024+row];
    }

    u64 ca_pref = 0;                   // prefetched h0seq cell for step t
    for (int t=0; t<S_LEN; ++t){
      const u64* pa = h0seq + (size_t)t*256 + lid;
      const int par = (t+1)&1;
      const u64* pf = hb1f + par*256 + lid;
      const u64* ps = hb1s + par*256 + lid;
      u64 ca=0, cb=0; bool ga=false, gb=false;
      if ((unsigned)(ca_pref>>32) == (unsigned)(t+1)){ ca=ca_pref; ga=true; }
      if (fast_ok){
        for (int k=0; k<FAST_TRIES && !(ga&&gb); ++k){
          if(!ga){ u64 v=aload64(pa);
                   if((unsigned)(v>>32)==(unsigned)(t+1)){ca=v;ga=true;} }
          if(!gb){ u64 v=load_sc0_u64(pf);
                   if((unsigned)(v>>32)==(unsigned)t){cb=v;gb=true;} }
        }
        if (!gb) fast_ok = false;
      }
      if (!(ga&&gb)){
        int it=0;
        while(!(ga&&gb)){
          if(!ga){ u64 v=aload64(pa);
                   if((unsigned)(v>>32)==(unsigned)(t+1)){ca=v;ga=true;} }
          if(!gb){ u64 v=aload64(ps);
                   if((unsigned)(v>>32)==(unsigned)t){cb=v;gb=true;} }
          if (++it > CAP) break;
        }
      }
      F2U xa; xa.u = (unsigned)ca; hx[lid] = xa.f;
      F2U hc; hc.u = (unsigned)cb; hh[lid] = hc.f;
      __syncthreads();
      // prefetch next h0seq cell; result drained by the post-publish barrier
      if (t+1 < S_LEN) ca_pref = aload64(pa + 256);
      float ir=0.f, iz=0.f, in_=0.f, hr=0.f, hz=0.f, hn=0.f;
      #pragma unroll
      for (int i=0;i<32;i++){
        f16x2 xv = hx[ksub + (i<<3)];
        f16x2 hv = hh[ksub + (i<<3)];
        ir = dot2(ur[i], xv, ir); iz = dot2(uz[i], xv, iz); in_ = dot2(un[i], xv, in_);
        hr = dot2(vr[i], hv, hr); hz = dot2(vz[i], hv, hz); hn  = dot2(vn[i], hv, hn);
      }
      #pragma unroll
      for (int d=1; d<8; d<<=1){
        ir += __shfl_xor(ir,d); iz += __shfl_xor(iz,d); in_ += __shfl_xor(in_,d);
        hr += __shfl_xor(hr,d); hz += __shfl_xor(hz,d); hn  += __shfl_xor(hn,d);
      }
      float hnew = 0.f;
      if (owner){
        float r  = sigf(ir + bir + hr + bhr);
        float z  = sigf(iz + biz + hz + bhz);
        float nl = tanh_fast(in_ + bin + r*(hn + bhn));
        hnew = (1.0f - z)*nl + z*(float)hh[row>>1][row&1];
      }
      float hp = __shfl(hnew, (lid & 192) + ((lid+8) & 63));
      if ((lid & 15) == 0){            // pair (row,row+1) -> one cell
        F2U pr; pr.f.x=(f16)hnew; pr.f.y=(f16)hp;
        const int j = (u<<4) + (lid>>4);
        const u64 tagged = ((u64)(unsigned)(t+1)<<32) | (u64)pr.u;
        store_u64(&hb1f[(t&1)*256 + j], tagged);
        apub64(&hb1s[(t&1)*256 + j], tagged);
        h1seq[(size_t)t*256 + j] = pr.f;   // plain; visible at kernel end
      }
      __syncthreads();
    }
  }
}

// ---------------- row-wise log_softmax over 2048, in place ----------------
__global__ __launch_bounds__(256) void logsoftmax_k(float* __restrict__ lp)
{
  const int t = blockIdx.x, lid = threadIdx.x;
  float* row = lp + (size_t)t*2048;
  float4 a = ((const float4*)row)[lid*2];
  float4 b = ((const float4*)row)[lid*2+1];
  float m = fmaxf(fmaxf(fmaxf(a.x,a.y),fmaxf(a.z,a.w)),
                  fmaxf(fmaxf(b.x,b.y),fmaxf(b.z,b.w)));
  #pragma unroll
  for (int off=1; off<64; off<<=1) m = fmaxf(m, __shfl_xor(m, off));
  __shared__ float redm[4], reds[4];
  const int lane = lid & 63, wvi = lid >> 6;
  if (lane==0) redm[wvi] = m;
  __syncthreads();
  m = fmaxf(fmaxf(redm[0],redm[1]), fmaxf(redm[2],redm[3]));
  float s = __expf(a.x-m)+__expf(a.y-m)+__expf(a.z-m)+__expf(a.w-m)
          + __expf(b.x-m)+__expf(b.y-m)+__expf(b.z-m)+__expf(b.w-m);
  #pragma unroll
  for (int off=1; off<64; off<<=1) s += __shfl_xor(s, off);
  if (lane==0) reds[wvi] = s;
  __syncthreads();
  s = reds[0]+reds[1]+reds[2]+reds[3];
  const float lg = m + __logf(s);
  a.x-=lg; a.y-=lg; a.z-=lg; a.w-=lg;
  b.x-=lg; b.y-=lg; b.z-=lg; b.w-=lg;
  ((float4*)row)[lid*2]   = a;
  ((float4*)row)[lid*2+1] = b;
}

// ---------------- values head: one wave per timestep ----------------
__global__ __launch_bounds__(256) void values_k(
    const f16* __restrict__ h1, const float* __restrict__ vW,
    const float* __restrict__ vb, float* __restrict__ outv, int S)
{
  const int gt = (int)((blockIdx.x*256 + threadIdx.x) >> 6);
  if (gt >= S) return;
  const int lane = threadIdx.x & 63;
  const f16* rowp = h1 + (size_t)gt*512;
  float s = 0.f;
  #pragma unroll
  for (int j=0;j<8;j++){
    const int k = lane + (j<<6);
    s += (float)rowp[k] * vW[k];
  }
  #pragma unroll
  for (int off=32; off; off>>=1) s += __shfl_down(s, off);
  if (lane==0) outv[gt] = s + vb[0];
}

extern "C" void kernel_launch(void* const* d_in, const int* in_sizes, int n_in,
                              void* d_out, int out_size, void* d_ws, size_t ws_size,
                              hipStream_t stream) {
  const float* init = (const float*)d_in[0];
  const float* emb  = (const float*)d_in[1];
  const float* Wih0 = (const float*)d_in[2];
  const float* Whh0 = (const float*)d_in[3];
  const float* bih0 = (const float*)d_in[4];
  const float* bhh0 = (const float*)d_in[5];
  const float* Wih1 = (const float*)d_in[6];
  const float* Whh1 = (const float*)d_in[7];
  const float* bih1 = (const float*)d_in[8];
  const float* bhh1 = (const float*)d_in[9];
  const float* actW = (const float*)d_in[10];
  const float* actb = (const float*)d_in[11];
  const float* valW = (const float*)d_in[12];
  const float* valb = (const float*)d_in[13];
  const int*   acts = (const int*)d_in[14];
  const int*   pars = (const int*)d_in[15];
  float* out = (float*)d_out;
  char*  w   = (char*)d_ws;

  f16* h1seq = (f16*)(w + H1SEQ_OFF);
  f16* actWh = (f16*)(w + ACTW_OFF);
  f16* Wih0h = (f16*)(w + WIH0_OFF);
  // d_out overlays (all dead before the logits GEMM writes d_out):
  f16* xi0   = (f16*)d_out;                                  // [0,48M)
  f16* X     = (f16*)((char*)d_out + 48u*1024*1024);         // [48M,80M)
  u64* h0seq = (u64*)((char*)d_out + 80u*1024*1024);         // [80M,112M)

  // clear h0seq tags (stale tags from prior replay would short-circuit ring1)
  hipMemsetAsync(h0seq, 0, (size_t)S_LEN*256*8, stream);
  gather_x<<<S_LEN, 256, 0, stream>>>(emb, acts, pars, X);
  cvt_k<<<1536, 256, 0, stream>>>(Wih0, Wih0h, 1536*1024);
  cvt_k<<<1024, 256, 0, stream>>>(actW, actWh, 2048*512);
  init_ctrl<<<1, 256, 0, stream>>>(init, w);

  // xi0 = X @ W_ih0^T + b_ih0   [S,1536]
  gemm_f16<f16><<<128*12, 256, 0, stream>>>(X, Wih0h, bih0, xi0, S_LEN, 1536, 1024);

  // fused two-layer scan: tagged rings with same-XCD fast path + fallback
  scan_rings<<<128, 256, 0, stream>>>(Whh0, bhh0, Wih1, bih1, Whh1, bhh1,
                                      init, xi0, h0seq, w);

  // logits = h1seq @ action_W^T + action_b -> d_out, then log_softmax in place
  gemm_f16<float><<<128*16, 256, 0, stream>>>(h1seq, actWh, actb, out, S_LEN, NRULES, 512);
  logsoftmax_k<<<S_LEN, 256, 0, stream>>>(out);
  values_k<<<S_LEN/4, 256, 0, stream>>>(h1seq, valW, valb, out + (size_t)S_LEN*NRULES, S_LEN);
}